// Round 1
// baseline (7488.510 us; speedup 1.0000x reference)
//
#include <hip/hip_runtime.h>
#include <math.h>

#define N_ 8
#define T_ 512
#define V_ 32000
#define D_ 512
#define DIN_ 1024
#define H_ 8
#define HD_ 64
#define L_ 2
#define F_ 2048

// ---------------- generic tiled f32 GEMM: C = A@B + bias (opt relu) -------
// A [M,K] row-major, B [K,N] row-major, C [M,N] row-major, bias [N] or null.
template <int BM, int BN, int BK, int TM, int TN, bool RELU>
__global__ __launch_bounds__((BM / TM) * (BN / TN)) void gemm_kernel(
    const float* __restrict__ A, const float* __restrict__ B,
    const float* __restrict__ bias, float* __restrict__ C, int M, int N,
    int K) {
  constexpr int THREADS = (BM / TM) * (BN / TN);
  __shared__ float As[BK][BM + 1];
  __shared__ float Bs[BK][BN + 1];
  const int tid = threadIdx.x;
  const int bm = blockIdx.y * BM;
  const int bn = blockIdx.x * BN;
  const int tcol = tid % (BN / TN);
  const int trow = tid / (BN / TN);

  float acc[TM][TN];
#pragma unroll
  for (int i = 0; i < TM; ++i)
#pragma unroll
    for (int j = 0; j < TN; ++j) acc[i][j] = 0.f;

  for (int k0 = 0; k0 < K; k0 += BK) {
#pragma unroll
    for (int i = tid; i < BM * BK; i += THREADS) {
      int m = i / BK, kk = i % BK;
      As[kk][m] = A[(size_t)(bm + m) * K + (k0 + kk)];
    }
#pragma unroll
    for (int i = tid; i < BK * BN; i += THREADS) {
      int kk = i / BN, n = i % BN;
      Bs[kk][n] = B[(size_t)(k0 + kk) * N + (bn + n)];
    }
    __syncthreads();
#pragma unroll
    for (int kk = 0; kk < BK; ++kk) {
      float a[TM], b[TN];
#pragma unroll
      for (int i = 0; i < TM; ++i) a[i] = As[kk][trow * TM + i];
#pragma unroll
      for (int j = 0; j < TN; ++j) b[j] = Bs[kk][tcol * TN + j];
#pragma unroll
      for (int i = 0; i < TM; ++i)
#pragma unroll
        for (int j = 0; j < TN; ++j) acc[i][j] += a[i] * b[j];
    }
    __syncthreads();
  }

#pragma unroll
  for (int i = 0; i < TM; ++i) {
    int m = bm + trow * TM + i;
#pragma unroll
    for (int j = 0; j < TN; ++j) {
      int n = bn + tcol * TN + j;
      float vv = acc[i][j] + (bias ? bias[n] : 0.f);
      if (RELU) vv = fmaxf(vv, 0.f);
      C[(size_t)m * N + n] = vv;
    }
  }
}

// ---------------- token + positional embedding ----------------------------
__global__ void embed_kernel(const int* __restrict__ captions,
                             const float* __restrict__ emb,
                             const float* __restrict__ pos,
                             float* __restrict__ x) {
  int idx = blockIdx.x * blockDim.x + threadIdx.x;  // over N*T*D
  int d = idx % D_;
  int nt = idx / D_;
  int t = nt % T_;
  int tok = captions[nt];
  x[idx] = emb[(size_t)tok * D_ + d] + pos[(size_t)t * D_ + d];
}

// ---------------- small matmul (tiny M): out[m,n] = A[m,:]@W[:,n]+b[n] ----
__global__ void small_mm_kernel(const float* __restrict__ A,
                                const float* __restrict__ W,
                                const float* __restrict__ bias,
                                float* __restrict__ out, int M, int K, int N) {
  int idx = blockIdx.x * blockDim.x + threadIdx.x;
  if (idx >= M * N) return;
  int m = idx / N, n = idx % N;
  float s = bias ? bias[n] : 0.f;
  for (int k = 0; k < K; ++k) s += A[(size_t)m * K + k] * W[(size_t)k * N + n];
  out[idx] = s;
}

// ---------------- causal self-attention, online softmax -------------------
// q,k,v,y layout: [N, T, D] with head h at cols [h*64, h*64+64)
__global__ __launch_bounds__(64) void sa_attn_kernel(
    const float* __restrict__ q, const float* __restrict__ k,
    const float* __restrict__ v, float* __restrict__ y) {
  const int t = blockIdx.x;
  const int h = blockIdx.y;
  const int n = blockIdx.z;
  const int lane = threadIdx.x;  // 64 lanes = HD
  const size_t base = (size_t)n * T_ * D_ + (size_t)h * HD_ + lane;
  const float qd = q[base + (size_t)t * D_] * 0.125f;  // 1/sqrt(64)
  float m = -1e30f, l = 0.f, acc = 0.f;
  for (int s = 0; s <= t; ++s) {
    float sc = qd * k[base + (size_t)s * D_];
#pragma unroll
    for (int off = 32; off; off >>= 1) sc += __shfl_xor(sc, off);
    float nm = fmaxf(m, sc);
    float p = __expf(sc - nm);
    float corr = __expf(m - nm);
    l = l * corr + p;
    acc = acc * corr + p * v[base + (size_t)s * D_];
    m = nm;
  }
  y[base + (size_t)t * D_] = acc / l;
}

// ---------------- fused residual add + LayerNorm (in-place on x) ----------
// resBroadcast: 0 -> res is [rows, D]; 1 -> res is [N, D], row -> n = row/T
__global__ __launch_bounds__(256) void ln_res_kernel(
    float* __restrict__ x, const float* __restrict__ res,
    const float* __restrict__ g, const float* __restrict__ b,
    int resBroadcast) {
  const int row = blockIdx.x;
  const int tid = threadIdx.x;  // 256, D=512 -> 2 per thread
  float* xr = x + (size_t)row * D_;
  const float* rr =
      res + (resBroadcast ? (size_t)(row / T_) * D_ : (size_t)row * D_);
  float v0 = xr[tid] + rr[tid];
  float v1 = xr[tid + 256] + rr[tid + 256];
  float s = v0 + v1, sq = v0 * v0 + v1 * v1;
#pragma unroll
  for (int off = 32; off; off >>= 1) {
    s += __shfl_xor(s, off);
    sq += __shfl_xor(sq, off);
  }
  __shared__ float ss[4], ssq[4];
  int wid = tid >> 6;
  if ((tid & 63) == 0) {
    ss[wid] = s;
    ssq[wid] = sq;
  }
  __syncthreads();
  s = ss[0] + ss[1] + ss[2] + ss[3];
  sq = ssq[0] + ssq[1] + ssq[2] + ssq[3];
  float mu = s * (1.f / D_);
  float var = sq * (1.f / D_) - mu * mu;
  float r = rsqrtf(var + 1e-5f);
  xr[tid] = (v0 - mu) * r * g[tid] + b[tid];
  xr[tid + 256] = (v1 - mu) * r * g[tid + 256] + b[tid + 256];
}

// ---------------- host-side orchestration ---------------------------------
static void gemm(const float* A, const float* B, const float* bias, float* C,
                 int M, int N, int K, bool relu, hipStream_t s) {
  dim3 grid(N / 64, M / 128);
  if (relu)
    hipLaunchKernelGGL((gemm_kernel<128, 64, 16, 8, 4, true>), grid, dim3(256),
                       0, s, A, B, bias, C, M, N, K);
  else
    hipLaunchKernelGGL((gemm_kernel<128, 64, 16, 8, 4, false>), grid, dim3(256),
                       0, s, A, B, bias, C, M, N, K);
}

extern "C" void kernel_launch(void* const* d_in, const int* in_sizes, int n_in,
                              void* d_out, int out_size, void* d_ws,
                              size_t ws_size, hipStream_t stream) {
  const float* features = (const float*)d_in[0];
  const int* captions = (const int*)d_in[1];
  const float* emb_table = (const float*)d_in[2];
  const float* pos_table = (const float*)d_in[3];
  const float* feat_W = (const float*)d_in[4];
  const float* feat_b = (const float*)d_in[5];
  const float* sa_qkv_W = (const float*)d_in[6];
  const float* sa_qkv_b = (const float*)d_in[7];
  const float* sa_o_W = (const float*)d_in[8];
  const float* sa_o_b = (const float*)d_in[9];
  const float* sa_ln = (const float*)d_in[10];
  const float* ca_qkv_W = (const float*)d_in[11];
  const float* ca_qkv_b = (const float*)d_in[12];
  const float* ca_o_W = (const float*)d_in[13];
  const float* ca_o_b = (const float*)d_in[14];
  const float* ca_ln = (const float*)d_in[15];
  const float* ff_W1 = (const float*)d_in[16];
  const float* ff_b1 = (const float*)d_in[17];
  const float* ff_W2 = (const float*)d_in[18];
  const float* ff_b2 = (const float*)d_in[19];
  const float* ff_ln = (const float*)d_in[20];
  const float* out_W = (const float*)d_in[21];
  const float* out_b = (const float*)d_in[22];

  const int ROWS = N_ * T_;  // 4096
  float* out = (float*)d_out;

  // small scratch in ws (~8.1 MB)
  float* x = (float*)d_ws;            // ROWS*D
  float* cond = x + (size_t)ROWS * D_;  // N*D
  float* vc = cond + N_ * D_;
  float* oc = vc + N_ * D_;

  // big scratch inside d_out (fully overwritten by final GEMM afterwards)
  float* q = out;                          // ROWS*D
  float* k = q + (size_t)ROWS * D_;        // ROWS*D
  float* v = k + (size_t)ROWS * D_;        // ROWS*D
  float* y = v + (size_t)ROWS * D_;        // ROWS*D
  float* ffh = y + (size_t)ROWS * D_;      // ROWS*F

  // cond = features @ feat_W + feat_b              [N, D]
  hipLaunchKernelGGL(small_mm_kernel, dim3((N_ * D_ + 255) / 256), dim3(256), 0,
                     stream, features, feat_W, feat_b, cond, N_, DIN_, D_);
  // x = emb[captions] + pos
  hipLaunchKernelGGL(embed_kernel, dim3(ROWS * D_ / 256), dim3(256), 0, stream,
                     captions, emb_table, pos_table, x);

  for (int l = 0; l < L_; ++l) {
    const float* Wq = sa_qkv_W + (size_t)(l * 3 + 0) * D_ * D_;
    const float* Wk = sa_qkv_W + (size_t)(l * 3 + 1) * D_ * D_;
    const float* Wv = sa_qkv_W + (size_t)(l * 3 + 2) * D_ * D_;
    const float* bq = sa_qkv_b + (size_t)(l * 3 + 0) * D_;
    const float* bk = sa_qkv_b + (size_t)(l * 3 + 1) * D_;
    const float* bv = sa_qkv_b + (size_t)(l * 3 + 2) * D_;

    gemm(x, Wq, bq, q, ROWS, D_, D_, false, stream);
    gemm(x, Wk, bk, k, ROWS, D_, D_, false, stream);
    gemm(x, Wv, bv, v, ROWS, D_, D_, false, stream);
    hipLaunchKernelGGL(sa_attn_kernel, dim3(T_, H_, N_), dim3(64), 0, stream, q,
                       k, v, y);
    // attn out projection -> reuse q as buffer
    gemm(y, sa_o_W + (size_t)l * D_ * D_, sa_o_b + (size_t)l * D_, q, ROWS, D_,
         D_, false, stream);
    hipLaunchKernelGGL(ln_res_kernel, dim3(ROWS), dim3(256), 0, stream, x, q,
                       sa_ln + (size_t)l * 2 * D_,
                       sa_ln + (size_t)l * 2 * D_ + D_, 0);

    // cross-attention: KV len == 1 -> softmax == 1 -> y = broadcast(v_c)
    hipLaunchKernelGGL(small_mm_kernel, dim3((N_ * D_ + 255) / 256), dim3(256),
                       0, stream, cond, ca_qkv_W + (size_t)(l * 3 + 2) * D_ * D_,
                       ca_qkv_b + (size_t)(l * 3 + 2) * D_, vc, N_, D_, D_);
    hipLaunchKernelGGL(small_mm_kernel, dim3((N_ * D_ + 255) / 256), dim3(256),
                       0, stream, vc, ca_o_W + (size_t)l * D_ * D_,
                       ca_o_b + (size_t)l * D_, oc, N_, D_, D_);
    hipLaunchKernelGGL(ln_res_kernel, dim3(ROWS), dim3(256), 0, stream, x, oc,
                       ca_ln + (size_t)l * 2 * D_,
                       ca_ln + (size_t)l * 2 * D_ + D_, 1);

    // FFN
    gemm(x, ff_W1 + (size_t)l * D_ * F_, ff_b1 + (size_t)l * F_, ffh, ROWS, F_,
         D_, true, stream);
    gemm(ffh, ff_W2 + (size_t)l * F_ * D_, ff_b2 + (size_t)l * D_, y, ROWS, D_,
         F_, false, stream);
    hipLaunchKernelGGL(ln_res_kernel, dim3(ROWS), dim3(256), 0, stream, x, y,
                       ff_ln + (size_t)l * 2 * D_,
                       ff_ln + (size_t)l * 2 * D_ + D_, 0);
  }

  // final vocab projection: out = x @ out_W + out_b   [4096, 32000]
  gemm(x, out_W, out_b, out, ROWS, V_, D_, false, stream);
}

// Round 2
// 3337.349 us; speedup vs baseline: 2.2439x; 2.2439x over previous
//
#include <hip/hip_runtime.h>
#include <math.h>
#include <stdint.h>

#define N_ 8
#define T_ 512
#define V_ 32000
#define D_ 512
#define DIN_ 1024
#define H_ 8
#define HD_ 64
#define L_ 2
#define F_ 2048

typedef __attribute__((ext_vector_type(8))) short short8;
typedef __attribute__((ext_vector_type(4))) float f32x4;

__device__ __forceinline__ short f2bf(float f) {
  uint32_t u = __builtin_bit_cast(uint32_t, f);
  u = (u + 0x7FFFu + ((u >> 16) & 1u)) >> 16;
  return (short)u;
}

// ============ transpose + f32->bf16: in = gridDim.z mats [K][N] f32,
// ============ out = [nmat*N][K] bf16
__global__ __launch_bounds__(256) void transpose_bf16_kernel(
    const float* __restrict__ in, short* __restrict__ out, int K, int N) {
  __shared__ float tile[64][65];
  const int mat = blockIdx.z;
  const int n0 = blockIdx.x * 64, k0 = blockIdx.y * 64;
  const float* src = in + (size_t)mat * K * N;
  const int tid = threadIdx.x;
  const int c = tid & 63, r4 = tid >> 6;
#pragma unroll
  for (int i = 0; i < 16; ++i) {
    int k = r4 + i * 4;
    tile[k][c] = src[(size_t)(k0 + k) * N + n0 + c];
  }
  __syncthreads();
#pragma unroll
  for (int i = 0; i < 16; ++i) {
    int n = r4 + i * 4;
    out[((size_t)mat * N + n0 + n) * K + k0 + c] = f2bf(tile[c][n]);
  }
}

// ============ MFMA GEMM: C[M,N] = A[M,K](f32) @ Bt[N,K](bf16)^T + bias ======
// 128x128 tile, BK=32, 256 threads (2x2 waves of 64x64), 16x16x32 bf16 MFMA.
template <bool RELU>
__global__ __launch_bounds__(256) void mfma_gemm_kernel(
    const float* __restrict__ A, const short* __restrict__ Bt,
    const float* __restrict__ bias, float* __restrict__ C, int M, int N,
    int K) {
  __shared__ short As[128 * 32];
  __shared__ short Bs[128 * 32];
  const int tid = threadIdx.x;
  const int lane = tid & 63, w = tid >> 6;
  const int wm = w >> 1, wn = w & 1;
  const int bm = blockIdx.y * 128, bn = blockIdx.x * 128;

  f32x4 acc[4][4];
#pragma unroll
  for (int i = 0; i < 4; ++i)
#pragma unroll
    for (int j = 0; j < 4; ++j) acc[i][j] = (f32x4)0.f;

  const int ar = tid >> 1, akh = (tid & 1) * 16;  // A-stage row / k-offset
  const float* aptr = A + (size_t)(bm + ar) * K + akh;
  const int brow0 = lane >> 2, bslot = (lane & 3) * 8;

  for (int k0 = 0; k0 < K; k0 += 32) {
    // stage B (bf16 [N][K]) via async global->LDS, 16B/lane, 2 waves-passes
#pragma unroll
    for (int g = 0; g < 2; ++g) {
      int row = g * 64 + w * 16;  // wave-uniform LDS base row
      const short* gp = Bt + (size_t)(bn + row + brow0) * K + k0 + bslot;
      __builtin_amdgcn_global_load_lds(
          (const __attribute__((address_space(1))) void*)gp,
          (__attribute__((address_space(3))) void*)&Bs[row * 32], 16, 0, 0);
    }
    // stage A: f32 -> bf16 in registers -> LDS
    {
      const float4* ap4 = (const float4*)(aptr + k0);
      float4 v0 = ap4[0], v1 = ap4[1], v2 = ap4[2], v3 = ap4[3];
      short8 lo = {f2bf(v0.x), f2bf(v0.y), f2bf(v0.z), f2bf(v0.w),
                   f2bf(v1.x), f2bf(v1.y), f2bf(v1.z), f2bf(v1.w)};
      short8 hi = {f2bf(v2.x), f2bf(v2.y), f2bf(v2.z), f2bf(v2.w),
                   f2bf(v3.x), f2bf(v3.y), f2bf(v3.z), f2bf(v3.w)};
      *(short8*)&As[ar * 32 + akh] = lo;
      *(short8*)&As[ar * 32 + akh + 8] = hi;
    }
    __syncthreads();
    short8 af[4], bf[4];
#pragma unroll
    for (int f = 0; f < 4; ++f) {
      af[f] = *(const short8*)&As[(wm * 64 + f * 16 + (lane & 15)) * 32 +
                                  (lane >> 4) * 8];
      bf[f] = *(const short8*)&Bs[(wn * 64 + f * 16 + (lane & 15)) * 32 +
                                  (lane >> 4) * 8];
    }
#pragma unroll
    for (int i = 0; i < 4; ++i)
#pragma unroll
      for (int j = 0; j < 4; ++j)
        acc[i][j] = __builtin_amdgcn_mfma_f32_16x16x32_bf16(af[i], bf[j],
                                                            acc[i][j], 0, 0, 0);
    __syncthreads();
  }
  // epilogue: C/D layout col=lane&15, row=(lane>>4)*4+r
#pragma unroll
  for (int j = 0; j < 4; ++j) {
    int col = bn + wn * 64 + j * 16 + (lane & 15);
    float bv = bias ? bias[col] : 0.f;
#pragma unroll
    for (int i = 0; i < 4; ++i) {
      int row0 = bm + wm * 64 + i * 16 + (lane >> 4) * 4;
#pragma unroll
      for (int r = 0; r < 4; ++r) {
        float v = acc[i][j][r] + bv;
        if (RELU) v = fmaxf(v, 0.f);
        C[(size_t)(row0 + r) * N + col] = v;
      }
    }
  }
}

// ============ fallback f32 SIMT GEMM (only if ws too small for out_Wt) ======
template <int BM, int BN, int BK, int TM, int TN>
__global__ __launch_bounds__((BM / TM) * (BN / TN)) void gemm_f32_kernel(
    const float* __restrict__ A, const float* __restrict__ B,
    const float* __restrict__ bias, float* __restrict__ C, int M, int N,
    int K) {
  constexpr int THREADS = (BM / TM) * (BN / TN);
  __shared__ float As[BK][BM + 1];
  __shared__ float Bs[BK][BN + 1];
  const int tid = threadIdx.x;
  const int bm = blockIdx.y * BM, bn = blockIdx.x * BN;
  const int tcol = tid % (BN / TN), trow = tid / (BN / TN);
  float acc[TM][TN];
#pragma unroll
  for (int i = 0; i < TM; ++i)
#pragma unroll
    for (int j = 0; j < TN; ++j) acc[i][j] = 0.f;
  for (int k0 = 0; k0 < K; k0 += BK) {
    for (int i = tid; i < BM * BK; i += THREADS) {
      int m = i / BK, kk = i % BK;
      As[kk][m] = A[(size_t)(bm + m) * K + (k0 + kk)];
    }
    for (int i = tid; i < BK * BN; i += THREADS) {
      int kk = i / BN, n = i % BN;
      Bs[kk][n] = B[(size_t)(k0 + kk) * N + (bn + n)];
    }
    __syncthreads();
#pragma unroll
    for (int kk = 0; kk < BK; ++kk) {
      float a[TM], b[TN];
#pragma unroll
      for (int i = 0; i < TM; ++i) a[i] = As[kk][trow * TM + i];
#pragma unroll
      for (int j = 0; j < TN; ++j) b[j] = Bs[kk][tcol * TN + j];
#pragma unroll
      for (int i = 0; i < TM; ++i)
#pragma unroll
        for (int j = 0; j < TN; ++j) acc[i][j] += a[i] * b[j];
    }
    __syncthreads();
  }
#pragma unroll
  for (int i = 0; i < TM; ++i) {
    int m = bm + trow * TM + i;
#pragma unroll
    for (int j = 0; j < TN; ++j) {
      int n = bn + tcol * TN + j;
      C[(size_t)m * N + n] = acc[i][j] + (bias ? bias[n] : 0.f);
    }
  }
}

// ============ token + positional embedding ==================================
__global__ void embed_kernel(const int* __restrict__ captions,
                             const float* __restrict__ emb,
                             const float* __restrict__ pos,
                             float* __restrict__ x) {
  int idx = blockIdx.x * blockDim.x + threadIdx.x;
  int d = idx % D_;
  int nt = idx / D_;
  int t = nt % T_;
  int tok = captions[nt];
  x[idx] = emb[(size_t)tok * D_ + d] + pos[(size_t)t * D_ + d];
}

// ============ small matmul (tiny M) =========================================
__global__ void small_mm_kernel(const float* __restrict__ A,
                                const float* __restrict__ W,
                                const float* __restrict__ bias,
                                float* __restrict__ out, int M, int K, int N) {
  int idx = blockIdx.x * blockDim.x + threadIdx.x;
  if (idx >= M * N) return;
  int m = idx / N, n = idx % N;
  float s = bias ? bias[n] : 0.f;
  for (int k = 0; k < K; ++k) s += A[(size_t)m * K + k] * W[(size_t)k * N + n];
  out[idx] = s;
}

// ============ causal attention: wave per (n,h,t), lane = s ==================
// qkv: [N*T][1536] (q|k|v), y: [N*T][512]
__global__ __launch_bounds__(64) void attn_kernel(const float* __restrict__ qkv,
                                                  float* __restrict__ y) {
  const int t = blockIdx.x, h = blockIdx.y, n = blockIdx.z;
  const int lane = threadIdx.x;
  const int QS = 3 * D_;
  const float4* q4 = (const float4*)(qkv + (size_t)(n * T_ + t) * QS + h * HD_);
  float4 qv[16];
#pragma unroll
  for (int g = 0; g < 16; ++g) {
    qv[g] = q4[g];
    qv[g].x *= 0.125f;
    qv[g].y *= 0.125f;
    qv[g].z *= 0.125f;
    qv[g].w *= 0.125f;
  }
  float m = -1e30f, l = 0.f, acc = 0.f;
  const float* kbase = qkv + (size_t)(n * T_) * QS + D_ + h * HD_;
  const float* vbase = qkv + (size_t)(n * T_) * QS + 2 * D_ + h * HD_ + lane;
  for (int s0 = 0; s0 <= t; s0 += 64) {
    const float4* k4 = (const float4*)(kbase + (size_t)(s0 + lane) * QS);
    float sc = 0.f;
#pragma unroll
    for (int g = 0; g < 16; ++g) {
      float4 kv = k4[g];
      sc += qv[g].x * kv.x + qv[g].y * kv.y + qv[g].z * kv.z + qv[g].w * kv.w;
    }
    if (s0 + lane > t) sc = -1e30f;
    float cmax = sc;
#pragma unroll
    for (int off = 32; off; off >>= 1) cmax = fmaxf(cmax, __shfl_xor(cmax, off));
    float mn = fmaxf(m, cmax);
    float p = __expf(sc - mn);
    float ssum = p;
#pragma unroll
    for (int off = 32; off; off >>= 1) ssum += __shfl_xor(ssum, off);
    float corr = __expf(m - mn);
    l = l * corr + ssum;
    acc *= corr;
    const float* vp = vbase + (size_t)s0 * QS;
#pragma unroll
    for (int s = 0; s < 64; ++s) {
      float ps = __shfl(p, s);
      acc += ps * vp[(size_t)s * QS];
    }
    m = mn;
  }
  y[(size_t)(n * T_ + t) * D_ + h * HD_ + lane] = acc / l;
}

// ============ fused residual add + LayerNorm (in-place on x) ================
__global__ __launch_bounds__(256) void ln_res_kernel(
    float* __restrict__ x, const float* __restrict__ res,
    const float* __restrict__ g, const float* __restrict__ b,
    int resBroadcast) {
  const int row = blockIdx.x;
  const int tid = threadIdx.x;
  float* xr = x + (size_t)row * D_;
  const float* rr =
      res + (resBroadcast ? (size_t)(row / T_) * D_ : (size_t)row * D_);
  float v0 = xr[tid] + rr[tid];
  float v1 = xr[tid + 256] + rr[tid + 256];
  float s = v0 + v1, sq = v0 * v0 + v1 * v1;
#pragma unroll
  for (int off = 32; off; off >>= 1) {
    s += __shfl_xor(s, off);
    sq += __shfl_xor(sq, off);
  }
  __shared__ float ss[4], ssq[4];
  int wid = tid >> 6;
  if ((tid & 63) == 0) {
    ss[wid] = s;
    ssq[wid] = sq;
  }
  __syncthreads();
  s = ss[0] + ss[1] + ss[2] + ss[3];
  sq = ssq[0] + ssq[1] + ssq[2] + ssq[3];
  float mu = s * (1.f / D_);
  float var = sq * (1.f / D_) - mu * mu;
  float r = rsqrtf(var + 1e-5f);
  xr[tid] = (v0 - mu) * r * g[tid] + b[tid];
  xr[tid + 256] = (v1 - mu) * r * g[tid + 256] + b[tid + 256];
}

// ============ host orchestration ============================================
extern "C" void kernel_launch(void* const* d_in, const int* in_sizes, int n_in,
                              void* d_out, int out_size, void* d_ws,
                              size_t ws_size, hipStream_t stream) {
  const float* features = (const float*)d_in[0];
  const int* captions = (const int*)d_in[1];
  const float* emb_table = (const float*)d_in[2];
  const float* pos_table = (const float*)d_in[3];
  const float* feat_W = (const float*)d_in[4];
  const float* feat_b = (const float*)d_in[5];
  const float* sa_qkv_W = (const float*)d_in[6];
  const float* sa_qkv_b = (const float*)d_in[7];
  const float* sa_o_W = (const float*)d_in[8];
  const float* sa_o_b = (const float*)d_in[9];
  const float* sa_ln = (const float*)d_in[10];
  const float* ca_qkv_W = (const float*)d_in[11];
  const float* ca_qkv_b = (const float*)d_in[12];
  const float* ca_o_W = (const float*)d_in[13];
  const float* ca_o_b = (const float*)d_in[14];
  const float* ca_ln = (const float*)d_in[15];
  const float* ff_W1 = (const float*)d_in[16];
  const float* ff_b1 = (const float*)d_in[17];
  const float* ff_W2 = (const float*)d_in[18];
  const float* ff_b2 = (const float*)d_in[19];
  const float* ff_ln = (const float*)d_in[20];
  const float* out_W = (const float*)d_in[21];
  const float* out_b = (const float*)d_in[22];

  const int ROWS = N_ * T_;  // 4096
  float* out = (float*)d_out;

  // ---- ws scratch: x + tiny cond buffers + (if room) transposed out_W bf16
  float* x = (float*)d_ws;
  float* cond = x + (size_t)ROWS * D_;
  float* vc = cond + N_ * D_;
  float* oc = vc + N_ * D_;
  short* outWt = (short*)(oc + N_ * D_);
  size_t ws_need =
      ((size_t)ROWS * D_ + 3 * N_ * D_) * 4 + (size_t)V_ * D_ * 2;
  const bool big_ws = ws_size >= ws_need;

  // ---- d_out scratch (all consumed before the final GEMM overwrites) ------
  float* qkv = out;                                // ROWS*1536
  float* y = qkv + (size_t)ROWS * 3 * D_;          // ROWS*D
  float* ffh = y + (size_t)ROWS * D_;              // ROWS*F
  float* tmp = ffh + (size_t)ROWS * F_;            // ROWS*D
  short* wq = (short*)(tmp + (size_t)ROWS * D_);   // L*3*D rows of [D]
  short* wo = wq + (size_t)L_ * 3 * D_ * D_;       // L*D rows of [D]
  short* w1 = wo + (size_t)L_ * D_ * D_;           // L*F rows of [D]
  short* w2 = w1 + (size_t)L_ * F_ * D_;           // L*D rows of [F]

  // ---- weight transposes + bf16 conversion --------------------------------
  hipLaunchKernelGGL(transpose_bf16_kernel, dim3(D_ / 64, D_ / 64, L_ * 3),
                     dim3(256), 0, stream, sa_qkv_W, wq, D_, D_);
  hipLaunchKernelGGL(transpose_bf16_kernel, dim3(D_ / 64, D_ / 64, L_),
                     dim3(256), 0, stream, sa_o_W, wo, D_, D_);
  hipLaunchKernelGGL(transpose_bf16_kernel, dim3(F_ / 64, D_ / 64, L_),
                     dim3(256), 0, stream, ff_W1, w1, D_, F_);
  hipLaunchKernelGGL(transpose_bf16_kernel, dim3(D_ / 64, F_ / 64, L_),
                     dim3(256), 0, stream, ff_W2, w2, F_, D_);
  if (big_ws)
    hipLaunchKernelGGL(transpose_bf16_kernel, dim3(V_ / 64, D_ / 64, 1),
                       dim3(256), 0, stream, out_W, outWt, D_, V_);

  auto mg = [&](const float* A, const short* Bt, const float* bias, float* C,
                int M, int Nn, int K, bool relu) {
    dim3 grid(Nn / 128, M / 128);
    if (relu)
      hipLaunchKernelGGL(mfma_gemm_kernel<true>, grid, dim3(256), 0, stream, A,
                         Bt, bias, C, M, Nn, K);
    else
      hipLaunchKernelGGL(mfma_gemm_kernel<false>, grid, dim3(256), 0, stream,
                         A, Bt, bias, C, M, Nn, K);
  };

  // ---- cond + embedding ---------------------------------------------------
  hipLaunchKernelGGL(small_mm_kernel, dim3((N_ * D_ + 255) / 256), dim3(256), 0,
                     stream, features, feat_W, feat_b, cond, N_, DIN_, D_);
  hipLaunchKernelGGL(embed_kernel, dim3(ROWS * D_ / 256), dim3(256), 0, stream,
                     captions, emb_table, pos_table, x);

  for (int l = 0; l < L_; ++l) {
    // fused QKV projection: [4096,512] @ [512,1536]
    mg(x, wq + (size_t)l * 3 * D_ * D_, sa_qkv_b + (size_t)l * 3 * D_, qkv,
       ROWS, 3 * D_, D_, false);
    hipLaunchKernelGGL(attn_kernel, dim3(T_, H_, N_), dim3(64), 0, stream, qkv,
                       y);
    mg(y, wo + (size_t)l * D_ * D_, sa_o_b + (size_t)l * D_, tmp, ROWS, D_, D_,
       false);
    hipLaunchKernelGGL(ln_res_kernel, dim3(ROWS), dim3(256), 0, stream, x, tmp,
                       sa_ln + (size_t)l * 2 * D_,
                       sa_ln + (size_t)l * 2 * D_ + D_, 0);

    // cross-attention (KV len 1 -> softmax == 1): v_c @ Wo broadcast
    hipLaunchKernelGGL(small_mm_kernel, dim3((N_ * D_ + 255) / 256), dim3(256),
                       0, stream, cond,
                       ca_qkv_W + (size_t)(l * 3 + 2) * D_ * D_,
                       ca_qkv_b + (size_t)(l * 3 + 2) * D_, vc, N_, D_, D_);
    hipLaunchKernelGGL(small_mm_kernel, dim3((N_ * D_ + 255) / 256), dim3(256),
                       0, stream, vc, ca_o_W + (size_t)l * D_ * D_,
                       ca_o_b + (size_t)l * D_, oc, N_, D_, D_);
    hipLaunchKernelGGL(ln_res_kernel, dim3(ROWS), dim3(256), 0, stream, x, oc,
                       ca_ln + (size_t)l * 2 * D_,
                       ca_ln + (size_t)l * 2 * D_ + D_, 1);

    // FFN
    mg(x, w1 + (size_t)l * F_ * D_, ff_b1 + (size_t)l * F_, ffh, ROWS, F_, D_,
       true);
    mg(ffh, w2 + (size_t)l * D_ * F_, ff_b2 + (size_t)l * D_, y, ROWS, D_, F_,
       false);
    hipLaunchKernelGGL(ln_res_kernel, dim3(ROWS), dim3(256), 0, stream, x, y,
                       ff_ln + (size_t)l * 2 * D_,
                       ff_ln + (size_t)l * 2 * D_ + D_, 0);
  }

  // ---- final vocab projection --------------------------------------------
  if (big_ws) {
    mg(x, outWt, out_b, out, ROWS, V_, D_, false);
  } else {
    dim3 grid(V_ / 64, ROWS / 128);
    hipLaunchKernelGGL((gemm_f32_kernel<128, 64, 16, 8, 4>), grid, dim3(256), 0,
                       stream, x, out_W, out_b, out, ROWS, V_, D_);
  }
}

// Round 3
// 1853.144 us; speedup vs baseline: 4.0410x; 1.8009x over previous
//
#include <hip/hip_runtime.h>
#include <math.h>
#include <stdint.h>

#define N_ 8
#define T_ 512
#define V_ 32000
#define D_ 512
#define DIN_ 1024
#define H_ 8
#define HD_ 64
#define L_ 2
#define F_ 2048

typedef __attribute__((ext_vector_type(8))) short short8;
typedef __attribute__((ext_vector_type(4))) float f32x4;

__device__ __forceinline__ short f2bf(float f) {
  uint32_t u = __builtin_bit_cast(uint32_t, f);
  u = (u + 0x7FFFu + ((u >> 16) & 1u)) >> 16;
  return (short)u;
}
__device__ __forceinline__ uint32_t pack_bf2(float a, float b) {
  return (uint32_t)(uint16_t)f2bf(a) | ((uint32_t)(uint16_t)f2bf(b) << 16);
}
// XOR-swizzled byte offset within a [row][128B] LDS tile (G4 conflict fix)
__device__ __forceinline__ int swzb(int row, int byteoff) {
  return row * 128 + (byteoff ^ ((row & 7) << 4));
}

// ============ transpose + f32->bf16: in = gridDim.z mats [K][N] f32 =========
__global__ __launch_bounds__(256) void transpose_bf16_kernel(
    const float* __restrict__ in, short* __restrict__ out, int K, int N) {
  __shared__ float tile[64][65];
  const int mat = blockIdx.z;
  const int n0 = blockIdx.x * 64, k0 = blockIdx.y * 64;
  const float* src = in + (size_t)mat * K * N;
  const int tid = threadIdx.x;
  const int c = tid & 63, r4 = tid >> 6;
#pragma unroll
  for (int i = 0; i < 16; ++i) {
    int k = r4 + i * 4;
    tile[k][c] = src[(size_t)(k0 + k) * N + n0 + c];
  }
  __syncthreads();
#pragma unroll
  for (int i = 0; i < 16; ++i) {
    int n = r4 + i * 4;
    out[((size_t)mat * N + n0 + n) * K + k0 + c] = f2bf(tile[c][n]);
  }
}

// ============ MFMA GEMM: C[M,N] = A[M,K](f32) @ Bt[N,K](bf16)^T + bias ======
template <bool RELU>
__global__ __launch_bounds__(256) void mfma_gemm_kernel(
    const float* __restrict__ A, const short* __restrict__ Bt,
    const float* __restrict__ bias, float* __restrict__ C, int M, int N,
    int K) {
  __shared__ short As[128 * 32];
  __shared__ short Bs[128 * 32];
  const int tid = threadIdx.x;
  const int lane = tid & 63, w = tid >> 6;
  const int wm = w >> 1, wn = w & 1;
  const int bm = blockIdx.y * 128, bn = blockIdx.x * 128;

  f32x4 acc[4][4];
#pragma unroll
  for (int i = 0; i < 4; ++i)
#pragma unroll
    for (int j = 0; j < 4; ++j) acc[i][j] = (f32x4)0.f;

  const int ar = tid >> 1, akh = (tid & 1) * 16;
  const float* aptr = A + (size_t)(bm + ar) * K + akh;
  const int brow0 = lane >> 2, bslot = (lane & 3) * 8;

  for (int k0 = 0; k0 < K; k0 += 32) {
#pragma unroll
    for (int g = 0; g < 2; ++g) {
      int row = g * 64 + w * 16;
      const short* gp = Bt + (size_t)(bn + row + brow0) * K + k0 + bslot;
      __builtin_amdgcn_global_load_lds(
          (const __attribute__((address_space(1))) void*)gp,
          (__attribute__((address_space(3))) void*)&Bs[row * 32], 16, 0, 0);
    }
    {
      const float4* ap4 = (const float4*)(aptr + k0);
      float4 v0 = ap4[0], v1 = ap4[1], v2 = ap4[2], v3 = ap4[3];
      short8 lo = {f2bf(v0.x), f2bf(v0.y), f2bf(v0.z), f2bf(v0.w),
                   f2bf(v1.x), f2bf(v1.y), f2bf(v1.z), f2bf(v1.w)};
      short8 hi = {f2bf(v2.x), f2bf(v2.y), f2bf(v2.z), f2bf(v2.w),
                   f2bf(v3.x), f2bf(v3.y), f2bf(v3.z), f2bf(v3.w)};
      *(short8*)&As[ar * 32 + akh] = lo;
      *(short8*)&As[ar * 32 + akh + 8] = hi;
    }
    __syncthreads();
    short8 af[4], bf[4];
#pragma unroll
    for (int f = 0; f < 4; ++f) {
      af[f] = *(const short8*)&As[(wm * 64 + f * 16 + (lane & 15)) * 32 +
                                  (lane >> 4) * 8];
      bf[f] = *(const short8*)&Bs[(wn * 64 + f * 16 + (lane & 15)) * 32 +
                                  (lane >> 4) * 8];
    }
#pragma unroll
    for (int i = 0; i < 4; ++i)
#pragma unroll
      for (int j = 0; j < 4; ++j)
        acc[i][j] = __builtin_amdgcn_mfma_f32_16x16x32_bf16(af[i], bf[j],
                                                            acc[i][j], 0, 0, 0);
    __syncthreads();
  }
#pragma unroll
  for (int j = 0; j < 4; ++j) {
    int col = bn + wn * 64 + j * 16 + (lane & 15);
    float bv = bias ? bias[col] : 0.f;
#pragma unroll
    for (int i = 0; i < 4; ++i) {
      int row0 = bm + wm * 64 + i * 16 + (lane >> 4) * 4;
#pragma unroll
      for (int r = 0; r < 4; ++r) {
        float v = acc[i][j][r] + bv;
        if (RELU) v = fmaxf(v, 0.f);
        C[(size_t)(row0 + r) * N + col] = v;
      }
    }
  }
}

// ============ fallback f32 SIMT GEMM ========================================
template <int BM, int BN, int BK, int TM, int TN>
__global__ __launch_bounds__((BM / TM) * (BN / TN)) void gemm_f32_kernel(
    const float* __restrict__ A, const float* __restrict__ B,
    const float* __restrict__ bias, float* __restrict__ C, int M, int N,
    int K) {
  constexpr int THREADS = (BM / TM) * (BN / TN);
  __shared__ float As[BK][BM + 1];
  __shared__ float Bs[BK][BN + 1];
  const int tid = threadIdx.x;
  const int bm = blockIdx.y * BM, bn = blockIdx.x * BN;
  const int tcol = tid % (BN / TN), trow = tid / (BN / TN);
  float acc[TM][TN];
#pragma unroll
  for (int i = 0; i < TM; ++i)
#pragma unroll
    for (int j = 0; j < TN; ++j) acc[i][j] = 0.f;
  for (int k0 = 0; k0 < K; k0 += BK) {
    for (int i = tid; i < BM * BK; i += THREADS) {
      int m = i / BK, kk = i % BK;
      As[kk][m] = A[(size_t)(bm + m) * K + (k0 + kk)];
    }
    for (int i = tid; i < BK * BN; i += THREADS) {
      int kk = i / BN, n = i % BN;
      Bs[kk][n] = B[(size_t)(k0 + kk) * N + (bn + n)];
    }
    __syncthreads();
#pragma unroll
    for (int kk = 0; kk < BK; ++kk) {
      float a[TM], b[TN];
#pragma unroll
      for (int i = 0; i < TM; ++i) a[i] = As[kk][trow * TM + i];
#pragma unroll
      for (int j = 0; j < TN; ++j) b[j] = Bs[kk][tcol * TN + j];
#pragma unroll
      for (int i = 0; i < TM; ++i)
#pragma unroll
        for (int j = 0; j < TN; ++j) acc[i][j] += a[i] * b[j];
    }
    __syncthreads();
  }
#pragma unroll
  for (int i = 0; i < TM; ++i) {
    int m = bm + trow * TM + i;
#pragma unroll
    for (int j = 0; j < TN; ++j) {
      int n = bn + tcol * TN + j;
      C[(size_t)m * N + n] = acc[i][j] + (bias ? bias[n] : 0.f);
    }
  }
}

// ============ token + positional embedding ==================================
__global__ void embed_kernel(const int* __restrict__ captions,
                             const float* __restrict__ emb,
                             const float* __restrict__ pos,
                             float* __restrict__ x) {
  int idx = blockIdx.x * blockDim.x + threadIdx.x;
  int d = idx % D_;
  int nt = idx / D_;
  int t = nt % T_;
  int tok = captions[nt];
  x[idx] = emb[(size_t)tok * D_ + d] + pos[(size_t)t * D_ + d];
}

// ============ small matmul (tiny M) =========================================
__global__ void small_mm_kernel(const float* __restrict__ A,
                                const float* __restrict__ W,
                                const float* __restrict__ bias,
                                float* __restrict__ out, int M, int K, int N) {
  int idx = blockIdx.x * blockDim.x + threadIdx.x;
  if (idx >= M * N) return;
  int m = idx / N, n = idx % N;
  float s = bias ? bias[n] : 0.f;
  for (int k = 0; k < K; ++k) s += A[(size_t)m * K + k] * W[(size_t)k * N + n];
  out[idx] = s;
}

// ============ MFMA flash attention ==========================================
// qkv: [N*T][1536] rows (q|k|v). Block = 4 waves, one (n,h,64-row Q tile).
// Per wave: 16 q rows. Swapped QK^T (S^T: col=t) -> in-register softmax ->
// P via per-wave LDS -> PV with V^T staged in LDS. All LDS rows 128B,
// XOR-swizzled to kill the 16-way bank conflict.
__global__ __launch_bounds__(256) void flash_attn_kernel(
    const float* __restrict__ qkv, float* __restrict__ y) {
  __shared__ short Ks[64 * 64];      // [s][d] bf16, swizzled
  __shared__ short Vt[64 * 64];      // [d][s] bf16, swizzled
  __shared__ short Ps[4][16 * 64];   // per-wave [t][s] bf16, swizzled
  const int t0 = blockIdx.x * 64;
  const int h = blockIdx.y, n = blockIdx.z;
  const int tid = threadIdx.x, lane = tid & 63, w = tid >> 6;
  const int lhi = lane >> 4, llo = lane & 15;
  char* KsB = (char*)Ks;
  char* VtB = (char*)Vt;
  char* PsB = (char*)Ps[w];

  // Q fragment: lane holds Q[t=llo][d=kc*32+lhi*8 ..+8], scaled by 1/8
  const float* qrow =
      qkv + (size_t)(n * T_ + t0 + w * 16 + llo) * 1536 + h * 64;
  short8 qf[2];
#pragma unroll
  for (int kc = 0; kc < 2; ++kc) {
    float4 a = *(const float4*)(qrow + kc * 32 + lhi * 8);
    float4 b = *(const float4*)(qrow + kc * 32 + lhi * 8 + 4);
    qf[kc] = short8{f2bf(a.x * 0.125f), f2bf(a.y * 0.125f), f2bf(a.z * 0.125f),
                    f2bf(a.w * 0.125f), f2bf(b.x * 0.125f), f2bf(b.y * 0.125f),
                    f2bf(b.z * 0.125f), f2bf(b.w * 0.125f)};
  }

  float m = -1e30f, l = 0.f;
  f32x4 acc[4];
#pragma unroll
  for (int dc = 0; dc < 4; ++dc) acc[dc] = (f32x4)0.f;

  const int sr = tid >> 2, sd0 = (tid & 3) * 16;  // staging: row, d-slice
  const int tg = t0 + w * 16 + llo;

  for (int s0 = 0; s0 <= t0; s0 += 64) {
    __syncthreads();  // prev chunk's LDS reads done before overwrite
    {
      const float* kg =
          qkv + (size_t)(n * T_ + s0 + sr) * 1536 + 512 + h * 64 + sd0;
      float4 k0 = *(const float4*)(kg), k1 = *(const float4*)(kg + 4),
             k2 = *(const float4*)(kg + 8), k3 = *(const float4*)(kg + 12);
      short8 klo = {f2bf(k0.x), f2bf(k0.y), f2bf(k0.z), f2bf(k0.w),
                    f2bf(k1.x), f2bf(k1.y), f2bf(k1.z), f2bf(k1.w)};
      short8 khi = {f2bf(k2.x), f2bf(k2.y), f2bf(k2.z), f2bf(k2.w),
                    f2bf(k3.x), f2bf(k3.y), f2bf(k3.z), f2bf(k3.w)};
      *(short8*)(KsB + swzb(sr, sd0 * 2)) = klo;
      *(short8*)(KsB + swzb(sr, sd0 * 2 + 16)) = khi;
      // V row -> transposed scatter into Vt[d][s]
      const float* vg = kg + 512;
      float va[16];
      *(float4*)&va[0] = *(const float4*)(vg);
      *(float4*)&va[4] = *(const float4*)(vg + 4);
      *(float4*)&va[8] = *(const float4*)(vg + 8);
      *(float4*)&va[12] = *(const float4*)(vg + 12);
#pragma unroll
      for (int j = 0; j < 16; ++j)
        *(short*)(VtB + swzb(sd0 + j, sr * 2)) = f2bf(va[j]);
    }
    __syncthreads();

    // S^T tiles: mfma(K, Q) -> per lane: t=llo, s=tile*16+lhi*4+r
    f32x4 st[4];
#pragma unroll
    for (int tile = 0; tile < 4; ++tile) {
      st[tile] = (f32x4)0.f;
#pragma unroll
      for (int kc = 0; kc < 2; ++kc) {
        short8 kf = *(const short8*)(KsB +
                                     swzb(tile * 16 + llo, kc * 64 + lhi * 16));
        st[tile] =
            __builtin_amdgcn_mfma_f32_16x16x32_bf16(kf, qf[kc], st[tile], 0, 0, 0);
      }
    }
    if (s0 == t0) {  // diagonal chunk: causal mask
#pragma unroll
      for (int tile = 0; tile < 4; ++tile)
#pragma unroll
        for (int r = 0; r < 4; ++r)
          if (s0 + tile * 16 + lhi * 4 + r > tg) st[tile][r] = -1e30f;
    }
    // online softmax over the 64 keys (4 in-reg x4 tiles + 2 shfl_xor)
    float cmax = -1e30f;
#pragma unroll
    for (int tile = 0; tile < 4; ++tile)
#pragma unroll
      for (int r = 0; r < 4; ++r) cmax = fmaxf(cmax, st[tile][r]);
    cmax = fmaxf(cmax, __shfl_xor(cmax, 16));
    cmax = fmaxf(cmax, __shfl_xor(cmax, 32));
    float mn = fmaxf(m, cmax);
    float corr = __expf(m - mn);
    float lsum = 0.f;
#pragma unroll
    for (int tile = 0; tile < 4; ++tile)
#pragma unroll
      for (int r = 0; r < 4; ++r) {
        float p = __expf(st[tile][r] - mn);
        st[tile][r] = p;
        lsum += p;
      }
    lsum += __shfl_xor(lsum, 16);
    lsum += __shfl_xor(lsum, 32);
    l = l * corr + lsum;
    m = mn;
    // P -> per-wave LDS as bf16 [t][s]
#pragma unroll
    for (int tile = 0; tile < 4; ++tile) {
      int base = swzb(llo, tile * 32 + lhi * 8);
      *(uint32_t*)(PsB + base) = pack_bf2(st[tile][0], st[tile][1]);
      *(uint32_t*)(PsB + base + 4) = pack_bf2(st[tile][2], st[tile][3]);
    }
    // rescale O (acc rows t = lhi*4+r; corr lives at lane t)
    float c0 = __shfl(corr, lhi * 4 + 0), c1 = __shfl(corr, lhi * 4 + 1);
    float c2 = __shfl(corr, lhi * 4 + 2), c3 = __shfl(corr, lhi * 4 + 3);
#pragma unroll
    for (int dc = 0; dc < 4; ++dc) {
      acc[dc][0] *= c0;
      acc[dc][1] *= c1;
      acc[dc][2] *= c2;
      acc[dc][3] *= c3;
    }
    // PV: A = P[t][s], B = V[s][d] (from Vt)
    short8 pf0 = *(const short8*)(PsB + swzb(llo, lhi * 16));
    short8 pf1 = *(const short8*)(PsB + swzb(llo, 64 + lhi * 16));
#pragma unroll
    for (int dc = 0; dc < 4; ++dc) {
      short8 vf0 = *(const short8*)(VtB + swzb(dc * 16 + llo, lhi * 16));
      short8 vf1 = *(const short8*)(VtB + swzb(dc * 16 + llo, 64 + lhi * 16));
      acc[dc] = __builtin_amdgcn_mfma_f32_16x16x32_bf16(pf0, vf0, acc[dc], 0, 0, 0);
      acc[dc] = __builtin_amdgcn_mfma_f32_16x16x32_bf16(pf1, vf1, acc[dc], 0, 0, 0);
    }
  }

  float linv = 1.f / l;
  float l0 = __shfl(linv, lhi * 4 + 0), l1 = __shfl(linv, lhi * 4 + 1);
  float l2 = __shfl(linv, lhi * 4 + 2), l3 = __shfl(linv, lhi * 4 + 3);
  float* yb = y + (size_t)(n * T_ + t0 + w * 16) * D_ + h * 64;
#pragma unroll
  for (int dc = 0; dc < 4; ++dc) {
    yb[(size_t)(lhi * 4 + 0) * D_ + dc * 16 + llo] = acc[dc][0] * l0;
    yb[(size_t)(lhi * 4 + 1) * D_ + dc * 16 + llo] = acc[dc][1] * l1;
    yb[(size_t)(lhi * 4 + 2) * D_ + dc * 16 + llo] = acc[dc][2] * l2;
    yb[(size_t)(lhi * 4 + 3) * D_ + dc * 16 + llo] = acc[dc][3] * l3;
  }
}

// ============ fused residual add + LayerNorm (in-place on x) ================
__global__ __launch_bounds__(256) void ln_res_kernel(
    float* __restrict__ x, const float* __restrict__ res,
    const float* __restrict__ g, const float* __restrict__ b,
    int resBroadcast) {
  const int row = blockIdx.x;
  const int tid = threadIdx.x;
  float* xr = x + (size_t)row * D_;
  const float* rr =
      res + (resBroadcast ? (size_t)(row / T_) * D_ : (size_t)row * D_);
  float v0 = xr[tid] + rr[tid];
  float v1 = xr[tid + 256] + rr[tid + 256];
  float s = v0 + v1, sq = v0 * v0 + v1 * v1;
#pragma unroll
  for (int off = 32; off; off >>= 1) {
    s += __shfl_xor(s, off);
    sq += __shfl_xor(sq, off);
  }
  __shared__ float ss[4], ssq[4];
  int wid = tid >> 6;
  if ((tid & 63) == 0) {
    ss[wid] = s;
    ssq[wid] = sq;
  }
  __syncthreads();
  s = ss[0] + ss[1] + ss[2] + ss[3];
  sq = ssq[0] + ssq[1] + ssq[2] + ssq[3];
  float mu = s * (1.f / D_);
  float var = sq * (1.f / D_) - mu * mu;
  float r = rsqrtf(var + 1e-5f);
  xr[tid] = (v0 - mu) * r * g[tid] + b[tid];
  xr[tid + 256] = (v1 - mu) * r * g[tid + 256] + b[tid + 256];
}

// ============ host orchestration ============================================
extern "C" void kernel_launch(void* const* d_in, const int* in_sizes, int n_in,
                              void* d_out, int out_size, void* d_ws,
                              size_t ws_size, hipStream_t stream) {
  const float* features = (const float*)d_in[0];
  const int* captions = (const int*)d_in[1];
  const float* emb_table = (const float*)d_in[2];
  const float* pos_table = (const float*)d_in[3];
  const float* feat_W = (const float*)d_in[4];
  const float* feat_b = (const float*)d_in[5];
  const float* sa_qkv_W = (const float*)d_in[6];
  const float* sa_qkv_b = (const float*)d_in[7];
  const float* sa_o_W = (const float*)d_in[8];
  const float* sa_o_b = (const float*)d_in[9];
  const float* sa_ln = (const float*)d_in[10];
  const float* ca_qkv_W = (const float*)d_in[11];
  const float* ca_qkv_b = (const float*)d_in[12];
  const float* ca_o_W = (const float*)d_in[13];
  const float* ca_o_b = (const float*)d_in[14];
  const float* ca_ln = (const float*)d_in[15];
  const float* ff_W1 = (const float*)d_in[16];
  const float* ff_b1 = (const float*)d_in[17];
  const float* ff_W2 = (const float*)d_in[18];
  const float* ff_b2 = (const float*)d_in[19];
  const float* ff_ln = (const float*)d_in[20];
  const float* out_W = (const float*)d_in[21];
  const float* out_b = (const float*)d_in[22];

  const int ROWS = N_ * T_;  // 4096
  float* out = (float*)d_out;

  // ---- ws scratch: x + tiny cond buffers + (if room) transposed out_W bf16
  float* x = (float*)d_ws;
  float* cond = x + (size_t)ROWS * D_;
  float* vc = cond + N_ * D_;
  float* oc = vc + N_ * D_;
  short* outWt = (short*)(oc + N_ * D_);
  size_t ws_need = ((size_t)ROWS * D_ + 3 * N_ * D_) * 4 + (size_t)V_ * D_ * 2;
  const bool big_ws = ws_size >= ws_need;

  // ---- d_out scratch (consumed before the final GEMM overwrites) ----------
  float* qkv = out;                               // ROWS*1536
  float* y = qkv + (size_t)ROWS * 3 * D_;         // ROWS*D
  float* ffh = y + (size_t)ROWS * D_;             // ROWS*F
  float* tmp = ffh + (size_t)ROWS * F_;           // ROWS*D
  short* wq = (short*)(tmp + (size_t)ROWS * D_);  // L*3*D rows of [D]
  short* wo = wq + (size_t)L_ * 3 * D_ * D_;      // L*D rows of [D]
  short* w1 = wo + (size_t)L_ * D_ * D_;          // L*F rows of [D]
  short* w2 = w1 + (size_t)L_ * F_ * D_;          // L*D rows of [F]

  // ---- weight transposes + bf16 conversion --------------------------------
  hipLaunchKernelGGL(transpose_bf16_kernel, dim3(D_ / 64, D_ / 64, L_ * 3),
                     dim3(256), 0, stream, sa_qkv_W, wq, D_, D_);
  hipLaunchKernelGGL(transpose_bf16_kernel, dim3(D_ / 64, D_ / 64, L_),
                     dim3(256), 0, stream, sa_o_W, wo, D_, D_);
  hipLaunchKernelGGL(transpose_bf16_kernel, dim3(F_ / 64, D_ / 64, L_),
                     dim3(256), 0, stream, ff_W1, w1, D_, F_);
  hipLaunchKernelGGL(transpose_bf16_kernel, dim3(D_ / 64, F_ / 64, L_),
                     dim3(256), 0, stream, ff_W2, w2, F_, D_);
  if (big_ws)
    hipLaunchKernelGGL(transpose_bf16_kernel, dim3(V_ / 64, D_ / 64, 1),
                       dim3(256), 0, stream, out_W, outWt, D_, V_);

  auto mg = [&](const float* A, const short* Bt, const float* bias, float* C,
                int M, int Nn, int K, bool relu) {
    dim3 grid(Nn / 128, M / 128);
    if (relu)
      hipLaunchKernelGGL(mfma_gemm_kernel<true>, grid, dim3(256), 0, stream, A,
                         Bt, bias, C, M, Nn, K);
    else
      hipLaunchKernelGGL(mfma_gemm_kernel<false>, grid, dim3(256), 0, stream,
                         A, Bt, bias, C, M, Nn, K);
  };

  // ---- cond + embedding ---------------------------------------------------
  hipLaunchKernelGGL(small_mm_kernel, dim3((N_ * D_ + 255) / 256), dim3(256), 0,
                     stream, features, feat_W, feat_b, cond, N_, DIN_, D_);
  hipLaunchKernelGGL(embed_kernel, dim3(ROWS * D_ / 256), dim3(256), 0, stream,
                     captions, emb_table, pos_table, x);

  for (int l = 0; l < L_; ++l) {
    // fused QKV projection: [4096,512] @ [512,1536]
    mg(x, wq + (size_t)l * 3 * D_ * D_, sa_qkv_b + (size_t)l * 3 * D_, qkv,
       ROWS, 3 * D_, D_, false);
    hipLaunchKernelGGL(flash_attn_kernel, dim3(T_ / 64, H_, N_), dim3(256), 0,
                       stream, qkv, y);
    mg(y, wo + (size_t)l * D_ * D_, sa_o_b + (size_t)l * D_, tmp, ROWS, D_, D_,
       false);
    hipLaunchKernelGGL(ln_res_kernel, dim3(ROWS), dim3(256), 0, stream, x, tmp,
                       sa_ln + (size_t)l * 2 * D_,
                       sa_ln + (size_t)l * 2 * D_ + D_, 0);

    // cross-attention (KV len 1 -> softmax == 1): v_c @ Wo broadcast
    hipLaunchKernelGGL(small_mm_kernel, dim3((N_ * D_ + 255) / 256), dim3(256),
                       0, stream, cond,
                       ca_qkv_W + (size_t)(l * 3 + 2) * D_ * D_,
                       ca_qkv_b + (size_t)(l * 3 + 2) * D_, vc, N_, D_, D_);
    hipLaunchKernelGGL(small_mm_kernel, dim3((N_ * D_ + 255) / 256), dim3(256),
                       0, stream, vc, ca_o_W + (size_t)l * D_ * D_,
                       ca_o_b + (size_t)l * D_, oc, N_, D_, D_);
    hipLaunchKernelGGL(ln_res_kernel, dim3(ROWS), dim3(256), 0, stream, x, oc,
                       ca_ln + (size_t)l * 2 * D_,
                       ca_ln + (size_t)l * 2 * D_ + D_, 1);

    // FFN
    mg(x, w1 + (size_t)l * F_ * D_, ff_b1 + (size_t)l * F_, ffh, ROWS, F_, D_,
       true);
    mg(ffh, w2 + (size_t)l * D_ * F_, ff_b2 + (size_t)l * D_, y, ROWS, D_, F_,
       false);
    hipLaunchKernelGGL(ln_res_kernel, dim3(ROWS), dim3(256), 0, stream, x, y,
                       ff_ln + (size_t)l * 2 * D_,
                       ff_ln + (size_t)l * 2 * D_ + D_, 0);
  }

  // ---- final vocab projection --------------------------------------------
  if (big_ws) {
    mg(x, outWt, out_b, out, ROWS, V_, D_, false);
  } else {
    dim3 grid(V_ / 64, ROWS / 128);
    hipLaunchKernelGGL((gemm_f32_kernel<128, 64, 16, 8, 4>), grid, dim3(256), 0,
                       stream, x, out_W, out_b, out, ROWS, V_, D_);
  }
}

// Round 4
// 779.760 us; speedup vs baseline: 9.6036x; 2.3766x over previous
//
#include <hip/hip_runtime.h>
#include <math.h>
#include <stdint.h>

#define N_ 8
#define T_ 512
#define V_ 32000
#define D_ 512
#define DIN_ 1024
#define H_ 8
#define HD_ 64
#define L_ 2
#define F_ 2048

typedef __attribute__((ext_vector_type(8))) short short8;
typedef __attribute__((ext_vector_type(4))) float f32x4;

__device__ __forceinline__ short f2bf(float f) {
  uint32_t u = __builtin_bit_cast(uint32_t, f);
  u = (u + 0x7FFFu + ((u >> 16) & 1u)) >> 16;
  return (short)u;
}
__device__ __forceinline__ uint32_t pack_bf2(float a, float b) {
  return (uint32_t)(uint16_t)f2bf(a) | ((uint32_t)(uint16_t)f2bf(b) << 16);
}
// XOR-swizzled byte offset within a [row][128B] LDS tile (G4 conflict fix)
__device__ __forceinline__ int swzb(int row, int byteoff) {
  return row * 128 + (byteoff ^ ((row & 7) << 4));
}

// ============ transpose + f32->bf16: in = gridDim.z mats [K][N] f32 =========
__global__ __launch_bounds__(256) void transpose_bf16_kernel(
    const float* __restrict__ in, short* __restrict__ out, int K, int N) {
  __shared__ float tile[64][65];
  const int mat = blockIdx.z;
  const int n0 = blockIdx.x * 64, k0 = blockIdx.y * 64;
  const float* src = in + (size_t)mat * K * N;
  const int tid = threadIdx.x;
  const int c = tid & 63, r4 = tid >> 6;
#pragma unroll
  for (int i = 0; i < 16; ++i) {
    int k = r4 + i * 4;
    tile[k][c] = src[(size_t)(k0 + k) * N + n0 + c];
  }
  __syncthreads();
#pragma unroll
  for (int i = 0; i < 16; ++i) {
    int n = r4 + i * 4;
    out[((size_t)mat * N + n0 + n) * K + k0 + c] = f2bf(tile[c][n]);
  }
}

// ============ MFMA GEMM: C[M,N] = A[M,K](f32) @ Bt[N,K](bf16)^T + bias ======
template <bool RELU>
__global__ __launch_bounds__(256) void mfma_gemm_kernel(
    const float* __restrict__ A, const short* __restrict__ Bt,
    const float* __restrict__ bias, float* __restrict__ C, int M, int N,
    int K) {
  __shared__ short As[128 * 32];
  __shared__ short Bs[128 * 32];
  const int tid = threadIdx.x;
  const int lane = tid & 63, w = tid >> 6;
  const int wm = w >> 1, wn = w & 1;
  const int bm = blockIdx.y * 128, bn = blockIdx.x * 128;

  f32x4 acc[4][4];
#pragma unroll
  for (int i = 0; i < 4; ++i)
#pragma unroll
    for (int j = 0; j < 4; ++j) acc[i][j] = (f32x4)0.f;

  const int ar = tid >> 1, akh = (tid & 1) * 16;
  const float* aptr = A + (size_t)(bm + ar) * K + akh;
  const int brow0 = lane >> 2, bslot = (lane & 3) * 8;

  for (int k0 = 0; k0 < K; k0 += 32) {
#pragma unroll
    for (int g = 0; g < 2; ++g) {
      int row = g * 64 + w * 16;
      const short* gp = Bt + (size_t)(bn + row + brow0) * K + k0 + bslot;
      __builtin_amdgcn_global_load_lds(
          (const __attribute__((address_space(1))) void*)gp,
          (__attribute__((address_space(3))) void*)&Bs[row * 32], 16, 0, 0);
    }
    {
      const float4* ap4 = (const float4*)(aptr + k0);
      float4 v0 = ap4[0], v1 = ap4[1], v2 = ap4[2], v3 = ap4[3];
      short8 lo = {f2bf(v0.x), f2bf(v0.y), f2bf(v0.z), f2bf(v0.w),
                   f2bf(v1.x), f2bf(v1.y), f2bf(v1.z), f2bf(v1.w)};
      short8 hi = {f2bf(v2.x), f2bf(v2.y), f2bf(v2.z), f2bf(v2.w),
                   f2bf(v3.x), f2bf(v3.y), f2bf(v3.z), f2bf(v3.w)};
      *(short8*)&As[ar * 32 + akh] = lo;
      *(short8*)&As[ar * 32 + akh + 8] = hi;
    }
    __syncthreads();
    short8 af[4], bf[4];
#pragma unroll
    for (int f = 0; f < 4; ++f) {
      af[f] = *(const short8*)&As[(wm * 64 + f * 16 + (lane & 15)) * 32 +
                                  (lane >> 4) * 8];
      bf[f] = *(const short8*)&Bs[(wn * 64 + f * 16 + (lane & 15)) * 32 +
                                  (lane >> 4) * 8];
    }
#pragma unroll
    for (int i = 0; i < 4; ++i)
#pragma unroll
      for (int j = 0; j < 4; ++j)
        acc[i][j] = __builtin_amdgcn_mfma_f32_16x16x32_bf16(af[i], bf[j],
                                                            acc[i][j], 0, 0, 0);
    __syncthreads();
  }
#pragma unroll
  for (int j = 0; j < 4; ++j) {
    int col = bn + wn * 64 + j * 16 + (lane & 15);
    float bv = bias ? bias[col] : 0.f;
#pragma unroll
    for (int i = 0; i < 4; ++i) {
      int row0 = bm + wm * 64 + i * 16 + (lane >> 4) * 4;
#pragma unroll
      for (int r = 0; r < 4; ++r) {
        float v = acc[i][j][r] + bv;
        if (RELU) v = fmaxf(v, 0.f);
        C[(size_t)(row0 + r) * N + col] = v;
      }
    }
  }
}

// ============ fallback f32 SIMT GEMM ========================================
template <int BM, int BN, int BK, int TM, int TN>
__global__ __launch_bounds__((BM / TM) * (BN / TN)) void gemm_f32_kernel(
    const float* __restrict__ A, const float* __restrict__ B,
    const float* __restrict__ bias, float* __restrict__ C, int M, int N,
    int K) {
  constexpr int THREADS = (BM / TM) * (BN / TN);
  __shared__ float As[BK][BM + 1];
  __shared__ float Bs[BK][BN + 1];
  const int tid = threadIdx.x;
  const int bm = blockIdx.y * BM, bn = blockIdx.x * BN;
  const int tcol = tid % (BN / TN), trow = tid / (BN / TN);
  float acc[TM][TN];
#pragma unroll
  for (int i = 0; i < TM; ++i)
#pragma unroll
    for (int j = 0; j < TN; ++j) acc[i][j] = 0.f;
  for (int k0 = 0; k0 < K; k0 += BK) {
    for (int i = tid; i < BM * BK; i += THREADS) {
      int m = i / BK, kk = i % BK;
      As[kk][m] = A[(size_t)(bm + m) * K + (k0 + kk)];
    }
    for (int i = tid; i < BK * BN; i += THREADS) {
      int kk = i / BN, n = i % BN;
      Bs[kk][n] = B[(size_t)(k0 + kk) * N + (bn + n)];
    }
    __syncthreads();
#pragma unroll
    for (int kk = 0; kk < BK; ++kk) {
      float a[TM], b[TN];
#pragma unroll
      for (int i = 0; i < TM; ++i) a[i] = As[kk][trow * TM + i];
#pragma unroll
      for (int j = 0; j < TN; ++j) b[j] = Bs[kk][tcol * TN + j];
#pragma unroll
      for (int i = 0; i < TM; ++i)
#pragma unroll
        for (int j = 0; j < TN; ++j) acc[i][j] += a[i] * b[j];
    }
    __syncthreads();
  }
#pragma unroll
  for (int i = 0; i < TM; ++i) {
    int m = bm + trow * TM + i;
#pragma unroll
    for (int j = 0; j < TN; ++j) {
      int n = bn + tcol * TN + j;
      C[(size_t)m * N + n] = acc[i][j] + (bias ? bias[n] : 0.f);
    }
  }
}

// ============ token + positional embedding ==================================
__global__ void embed_kernel(const int* __restrict__ captions,
                             const float* __restrict__ emb,
                             const float* __restrict__ pos,
                             float* __restrict__ x) {
  int idx = blockIdx.x * blockDim.x + threadIdx.x;
  int d = idx % D_;
  int nt = idx / D_;
  int t = nt % T_;
  int tok = captions[nt];
  x[idx] = emb[(size_t)tok * D_ + d] + pos[(size_t)t * D_ + d];
}

// ============ tiny-M matmul: one wave per output element, lanes split K =====
__global__ __launch_bounds__(256) void wave_mm_kernel(
    const float* __restrict__ A, const float* __restrict__ W,
    const float* __restrict__ bias, float* __restrict__ out, int M, int K,
    int N) {
  const int widx = blockIdx.x * 4 + (threadIdx.x >> 6);  // output element id
  const int lane = threadIdx.x & 63;
  if (widx >= M * N) return;
  const int m = widx / N, n = widx % N;
  const float* a = A + (size_t)m * K;
  const float* w = W + n;
  float s = 0.f;
  for (int k = lane; k < K; k += 64) s += a[k] * w[(size_t)k * N];
#pragma unroll
  for (int off = 32; off; off >>= 1) s += __shfl_xor(s, off);
  if (lane == 0) out[widx] = s + (bias ? bias[n] : 0.f);
}

// ============ MFMA flash attention ==========================================
// qkv: [N*T][1536] rows (q|k|v). Block = 4 waves, one (n,h,64-row Q tile).
__global__ __launch_bounds__(256) void flash_attn_kernel(
    const float* __restrict__ qkv, float* __restrict__ y) {
  __shared__ short Ks[64 * 64];      // [s][d] bf16, swizzled
  __shared__ short Vt[64 * 64];      // [d][s] bf16, swizzled
  __shared__ short Ps[4][16 * 64];   // per-wave [t][s] bf16, swizzled
  const int t0 = blockIdx.x * 64;
  const int h = blockIdx.y, n = blockIdx.z;
  const int tid = threadIdx.x, lane = tid & 63, w = tid >> 6;
  const int lhi = lane >> 4, llo = lane & 15;
  char* KsB = (char*)Ks;
  char* VtB = (char*)Vt;
  char* PsB = (char*)Ps[w];

  const float* qrow =
      qkv + (size_t)(n * T_ + t0 + w * 16 + llo) * 1536 + h * 64;
  short8 qf[2];
#pragma unroll
  for (int kc = 0; kc < 2; ++kc) {
    float4 a = *(const float4*)(qrow + kc * 32 + lhi * 8);
    float4 b = *(const float4*)(qrow + kc * 32 + lhi * 8 + 4);
    qf[kc] = short8{f2bf(a.x * 0.125f), f2bf(a.y * 0.125f), f2bf(a.z * 0.125f),
                    f2bf(a.w * 0.125f), f2bf(b.x * 0.125f), f2bf(b.y * 0.125f),
                    f2bf(b.z * 0.125f), f2bf(b.w * 0.125f)};
  }

  float m = -1e30f, l = 0.f;
  f32x4 acc[4];
#pragma unroll
  for (int dc = 0; dc < 4; ++dc) acc[dc] = (f32x4)0.f;

  const int sr = tid >> 2, sd0 = (tid & 3) * 16;
  const int tg = t0 + w * 16 + llo;

  for (int s0 = 0; s0 <= t0; s0 += 64) {
    __syncthreads();
    {
      const float* kg =
          qkv + (size_t)(n * T_ + s0 + sr) * 1536 + 512 + h * 64 + sd0;
      float4 k0 = *(const float4*)(kg), k1 = *(const float4*)(kg + 4),
             k2 = *(const float4*)(kg + 8), k3 = *(const float4*)(kg + 12);
      short8 klo = {f2bf(k0.x), f2bf(k0.y), f2bf(k0.z), f2bf(k0.w),
                    f2bf(k1.x), f2bf(k1.y), f2bf(k1.z), f2bf(k1.w)};
      short8 khi = {f2bf(k2.x), f2bf(k2.y), f2bf(k2.z), f2bf(k2.w),
                    f2bf(k3.x), f2bf(k3.y), f2bf(k3.z), f2bf(k3.w)};
      *(short8*)(KsB + swzb(sr, sd0 * 2)) = klo;
      *(short8*)(KsB + swzb(sr, sd0 * 2 + 16)) = khi;
      const float* vg = kg + 512;
      float va[16];
      *(float4*)&va[0] = *(const float4*)(vg);
      *(float4*)&va[4] = *(const float4*)(vg + 4);
      *(float4*)&va[8] = *(const float4*)(vg + 8);
      *(float4*)&va[12] = *(const float4*)(vg + 12);
#pragma unroll
      for (int j = 0; j < 16; ++j)
        *(short*)(VtB + swzb(sd0 + j, sr * 2)) = f2bf(va[j]);
    }
    __syncthreads();

    f32x4 st[4];
#pragma unroll
    for (int tile = 0; tile < 4; ++tile) {
      st[tile] = (f32x4)0.f;
#pragma unroll
      for (int kc = 0; kc < 2; ++kc) {
        short8 kf = *(const short8*)(KsB +
                                     swzb(tile * 16 + llo, kc * 64 + lhi * 16));
        st[tile] =
            __builtin_amdgcn_mfma_f32_16x16x32_bf16(kf, qf[kc], st[tile], 0, 0, 0);
      }
    }
    if (s0 == t0) {
#pragma unroll
      for (int tile = 0; tile < 4; ++tile)
#pragma unroll
        for (int r = 0; r < 4; ++r)
          if (s0 + tile * 16 + lhi * 4 + r > tg) st[tile][r] = -1e30f;
    }
    float cmax = -1e30f;
#pragma unroll
    for (int tile = 0; tile < 4; ++tile)
#pragma unroll
      for (int r = 0; r < 4; ++r) cmax = fmaxf(cmax, st[tile][r]);
    cmax = fmaxf(cmax, __shfl_xor(cmax, 16));
    cmax = fmaxf(cmax, __shfl_xor(cmax, 32));
    float mn = fmaxf(m, cmax);
    float corr = __expf(m - mn);
    float lsum = 0.f;
#pragma unroll
    for (int tile = 0; tile < 4; ++tile)
#pragma unroll
      for (int r = 0; r < 4; ++r) {
        float p = __expf(st[tile][r] - mn);
        st[tile][r] = p;
        lsum += p;
      }
    lsum += __shfl_xor(lsum, 16);
    lsum += __shfl_xor(lsum, 32);
    l = l * corr + lsum;
    m = mn;
#pragma unroll
    for (int tile = 0; tile < 4; ++tile) {
      int base = swzb(llo, tile * 32 + lhi * 8);
      *(uint32_t*)(PsB + base) = pack_bf2(st[tile][0], st[tile][1]);
      *(uint32_t*)(PsB + base + 4) = pack_bf2(st[tile][2], st[tile][3]);
    }
    float c0 = __shfl(corr, lhi * 4 + 0), c1 = __shfl(corr, lhi * 4 + 1);
    float c2 = __shfl(corr, lhi * 4 + 2), c3 = __shfl(corr, lhi * 4 + 3);
#pragma unroll
    for (int dc = 0; dc < 4; ++dc) {
      acc[dc][0] *= c0;
      acc[dc][1] *= c1;
      acc[dc][2] *= c2;
      acc[dc][3] *= c3;
    }
    short8 pf0 = *(const short8*)(PsB + swzb(llo, lhi * 16));
    short8 pf1 = *(const short8*)(PsB + swzb(llo, 64 + lhi * 16));
#pragma unroll
    for (int dc = 0; dc < 4; ++dc) {
      short8 vf0 = *(const short8*)(VtB + swzb(dc * 16 + llo, lhi * 16));
      short8 vf1 = *(const short8*)(VtB + swzb(dc * 16 + llo, 64 + lhi * 16));
      acc[dc] = __builtin_amdgcn_mfma_f32_16x16x32_bf16(pf0, vf0, acc[dc], 0, 0, 0);
      acc[dc] = __builtin_amdgcn_mfma_f32_16x16x32_bf16(pf1, vf1, acc[dc], 0, 0, 0);
    }
  }

  float linv = 1.f / l;
  float l0 = __shfl(linv, lhi * 4 + 0), l1 = __shfl(linv, lhi * 4 + 1);
  float l2 = __shfl(linv, lhi * 4 + 2), l3 = __shfl(linv, lhi * 4 + 3);
  float* yb = y + (size_t)(n * T_ + t0 + w * 16) * D_ + h * 64;
#pragma unroll
  for (int dc = 0; dc < 4; ++dc) {
    yb[(size_t)(lhi * 4 + 0) * D_ + dc * 16 + llo] = acc[dc][0] * l0;
    yb[(size_t)(lhi * 4 + 1) * D_ + dc * 16 + llo] = acc[dc][1] * l1;
    yb[(size_t)(lhi * 4 + 2) * D_ + dc * 16 + llo] = acc[dc][2] * l2;
    yb[(size_t)(lhi * 4 + 3) * D_ + dc * 16 + llo] = acc[dc][3] * l3;
  }
}

// ============ fused residual add + LayerNorm (in-place on x) ================
__global__ __launch_bounds__(256) void ln_res_kernel(
    float* __restrict__ x, const float* __restrict__ res,
    const float* __restrict__ g, const float* __restrict__ b,
    int resBroadcast) {
  const int row = blockIdx.x;
  const int tid = threadIdx.x;
  float* xr = x + (size_t)row * D_;
  const float* rr =
      res + (resBroadcast ? (size_t)(row / T_) * D_ : (size_t)row * D_);
  float v0 = xr[tid] + rr[tid];
  float v1 = xr[tid + 256] + rr[tid + 256];
  float s = v0 + v1, sq = v0 * v0 + v1 * v1;
#pragma unroll
  for (int off = 32; off; off >>= 1) {
    s += __shfl_xor(s, off);
    sq += __shfl_xor(sq, off);
  }
  __shared__ float ss[4], ssq[4];
  int wid = tid >> 6;
  if ((tid & 63) == 0) {
    ss[wid] = s;
    ssq[wid] = sq;
  }
  __syncthreads();
  s = ss[0] + ss[1] + ss[2] + ss[3];
  sq = ssq[0] + ssq[1] + ssq[2] + ssq[3];
  float mu = s * (1.f / D_);
  float var = sq * (1.f / D_) - mu * mu;
  float r = rsqrtf(var + 1e-5f);
  xr[tid] = (v0 - mu) * r * g[tid] + b[tid];
  xr[tid + 256] = (v1 - mu) * r * g[tid + 256] + b[tid + 256];
}

// ============ host orchestration ============================================
extern "C" void kernel_launch(void* const* d_in, const int* in_sizes, int n_in,
                              void* d_out, int out_size, void* d_ws,
                              size_t ws_size, hipStream_t stream) {
  const float* features = (const float*)d_in[0];
  const int* captions = (const int*)d_in[1];
  const float* emb_table = (const float*)d_in[2];
  const float* pos_table = (const float*)d_in[3];
  const float* feat_W = (const float*)d_in[4];
  const float* feat_b = (const float*)d_in[5];
  const float* sa_qkv_W = (const float*)d_in[6];
  const float* sa_qkv_b = (const float*)d_in[7];
  const float* sa_o_W = (const float*)d_in[8];
  const float* sa_o_b = (const float*)d_in[9];
  const float* sa_ln = (const float*)d_in[10];
  const float* ca_qkv_W = (const float*)d_in[11];
  const float* ca_qkv_b = (const float*)d_in[12];
  const float* ca_o_W = (const float*)d_in[13];
  const float* ca_o_b = (const float*)d_in[14];
  const float* ca_ln = (const float*)d_in[15];
  const float* ff_W1 = (const float*)d_in[16];
  const float* ff_b1 = (const float*)d_in[17];
  const float* ff_W2 = (const float*)d_in[18];
  const float* ff_b2 = (const float*)d_in[19];
  const float* ff_ln = (const float*)d_in[20];
  const float* out_W = (const float*)d_in[21];
  const float* out_b = (const float*)d_in[22];

  const int ROWS = N_ * T_;  // 4096
  float* out = (float*)d_out;

  // ---- ws scratch ---------------------------------------------------------
  float* x = (float*)d_ws;
  float* cond = x + (size_t)ROWS * D_;
  float* vc = cond + N_ * D_;
  float* oc = vc + N_ * D_;
  short* outWt = (short*)(oc + N_ * D_);
  size_t ws_need = ((size_t)ROWS * D_ + 3 * N_ * D_) * 4 + (size_t)V_ * D_ * 2;
  const bool big_ws = ws_size >= ws_need;

  // ---- d_out scratch (consumed before the final GEMM overwrites) ----------
  float* qkv = out;                               // ROWS*1536
  float* y = qkv + (size_t)ROWS * 3 * D_;         // ROWS*D
  float* ffh = y + (size_t)ROWS * D_;             // ROWS*F
  float* tmp = ffh + (size_t)ROWS * F_;           // ROWS*D
  short* wq = (short*)(tmp + (size_t)ROWS * D_);  // L*3*D rows of [D]
  short* wo = wq + (size_t)L_ * 3 * D_ * D_;      // L*D rows of [D]
  short* w1 = wo + (size_t)L_ * D_ * D_;          // L*F rows of [D]
  short* w2 = w1 + (size_t)L_ * F_ * D_;          // L*D rows of [F]

  // ---- weight transposes + bf16 conversion --------------------------------
  hipLaunchKernelGGL(transpose_bf16_kernel, dim3(D_ / 64, D_ / 64, L_ * 3),
                     dim3(256), 0, stream, sa_qkv_W, wq, D_, D_);
  hipLaunchKernelGGL(transpose_bf16_kernel, dim3(F_ / 64, D_ / 64, L_),
                     dim3(256), 0, stream, ff_W1, w1, D_, F_);
  hipLaunchKernelGGL(transpose_bf16_kernel, dim3(D_ / 64, D_ / 64, L_),
                     dim3(256), 0, stream, sa_o_W, wo, D_, D_);
  hipLaunchKernelGGL(transpose_bf16_kernel, dim3(D_ / 64, F_ / 64, L_),
                     dim3(256), 0, stream, ff_W2, w2, F_, D_);
  if (big_ws)
    hipLaunchKernelGGL(transpose_bf16_kernel, dim3(V_ / 64, D_ / 64, 1),
                       dim3(256), 0, stream, out_W, outWt, D_, V_);

  auto mg = [&](const float* A, const short* Bt, const float* bias, float* C,
                int M, int Nn, int K, bool relu) {
    dim3 grid(Nn / 128, M / 128);
    if (relu)
      hipLaunchKernelGGL(mfma_gemm_kernel<true>, grid, dim3(256), 0, stream, A,
                         Bt, bias, C, M, Nn, K);
    else
      hipLaunchKernelGGL(mfma_gemm_kernel<false>, grid, dim3(256), 0, stream,
                         A, Bt, bias, C, M, Nn, K);
  };
  auto wmm = [&](const float* A, const float* W, const float* bias, float* C,
                 int M, int K, int Nn) {
    hipLaunchKernelGGL(wave_mm_kernel, dim3((M * Nn + 3) / 4), dim3(256), 0,
                       stream, A, W, bias, C, M, K, Nn);
  };

  // ---- cond + embedding ---------------------------------------------------
  wmm(features, feat_W, feat_b, cond, N_, DIN_, D_);
  hipLaunchKernelGGL(embed_kernel, dim3(ROWS * D_ / 256), dim3(256), 0, stream,
                     captions, emb_table, pos_table, x);

  for (int l = 0; l < L_; ++l) {
    // fused QKV projection: [4096,512] @ [512,1536]
    mg(x, wq + (size_t)l * 3 * D_ * D_, sa_qkv_b + (size_t)l * 3 * D_, qkv,
       ROWS, 3 * D_, D_, false);
    hipLaunchKernelGGL(flash_attn_kernel, dim3(T_ / 64, H_, N_), dim3(256), 0,
                       stream, qkv, y);
    mg(y, wo + (size_t)l * D_ * D_, sa_o_b + (size_t)l * D_, tmp, ROWS, D_, D_,
       false);
    hipLaunchKernelGGL(ln_res_kernel, dim3(ROWS), dim3(256), 0, stream, x, tmp,
                       sa_ln + (size_t)l * 2 * D_,
                       sa_ln + (size_t)l * 2 * D_ + D_, 0);

    // cross-attention (KV len 1 -> softmax == 1): v_c @ Wo broadcast
    wmm(cond, ca_qkv_W + (size_t)(l * 3 + 2) * D_ * D_,
        ca_qkv_b + (size_t)(l * 3 + 2) * D_, vc, N_, D_, D_);
    wmm(vc, ca_o_W + (size_t)l * D_ * D_, ca_o_b + (size_t)l * D_, oc, N_, D_,
        D_);
    hipLaunchKernelGGL(ln_res_kernel, dim3(ROWS), dim3(256), 0, stream, x, oc,
                       ca_ln + (size_t)l * 2 * D_,
                       ca_ln + (size_t)l * 2 * D_ + D_, 1);

    // FFN
    mg(x, w1 + (size_t)l * F_ * D_, ff_b1 + (size_t)l * F_, ffh, ROWS, F_, D_,
       true);
    mg(ffh, w2 + (size_t)l * D_ * F_, ff_b2 + (size_t)l * D_, y, ROWS, D_, F_,
       false);
    hipLaunchKernelGGL(ln_res_kernel, dim3(ROWS), dim3(256), 0, stream, x, y,
                       ff_ln + (size_t)l * 2 * D_,
                       ff_ln + (size_t)l * 2 * D_ + D_, 0);
  }

  // ---- final vocab projection --------------------------------------------
  if (big_ws) {
    mg(x, outWt, out_b, out, ROWS, V_, D_, false);
  } else {
    dim3 grid(V_ / 64, ROWS / 128);
    hipLaunchKernelGGL((gemm_f32_kernel<128, 64, 16, 8, 4>), grid, dim3(256), 0,
                       stream, x, out_W, out_b, out, ROWS, V_, D_);
  }
}

// Round 5
// 587.518 us; speedup vs baseline: 12.7460x; 1.3272x over previous
//
#include <hip/hip_runtime.h>
#include <math.h>
#include <stdint.h>

#define N_ 8
#define T_ 512
#define V_ 32000
#define D_ 512
#define DIN_ 1024
#define H_ 8
#define HD_ 64
#define L_ 2
#define F_ 2048

typedef __attribute__((ext_vector_type(8))) short short8;
typedef __attribute__((ext_vector_type(4))) float f32x4;

__device__ __forceinline__ short f2bf(float f) {
  uint32_t u = __builtin_bit_cast(uint32_t, f);
  u = (u + 0x7FFFu + ((u >> 16) & 1u)) >> 16;
  return (short)u;
}
__device__ __forceinline__ uint32_t pack_bf2(float a, float b) {
  return (uint32_t)(uint16_t)f2bf(a) | ((uint32_t)(uint16_t)f2bf(b) << 16);
}
// XOR-swizzled byte offset within a [row][128B] LDS tile (G4 conflict fix)
__device__ __forceinline__ int swzb(int row, int byteoff) {
  return row * 128 + (byteoff ^ ((row & 7) << 4));
}

// ============ transpose + f32->bf16: in = gridDim.z mats [K][N] f32 =========
__global__ __launch_bounds__(256) void transpose_bf16_kernel(
    const float* __restrict__ in, short* __restrict__ out, int K, int N) {
  __shared__ float tile[64][65];
  const int mat = blockIdx.z;
  const int n0 = blockIdx.x * 64, k0 = blockIdx.y * 64;
  const float* src = in + (size_t)mat * K * N;
  const int tid = threadIdx.x;
  const int c = tid & 63, r4 = tid >> 6;
#pragma unroll
  for (int i = 0; i < 16; ++i) {
    int k = r4 + i * 4;
    tile[k][c] = src[(size_t)(k0 + k) * N + n0 + c];
  }
  __syncthreads();
#pragma unroll
  for (int i = 0; i < 16; ++i) {
    int n = r4 + i * 4;
    out[((size_t)mat * N + n0 + n) * K + k0 + c] = f2bf(tile[c][n]);
  }
}

// ============ bf16 MFMA GEMM: C[M,N] = A[M,K](bf16) @ Bt[N,K](bf16)^T + b ===
// Both operands staged via global_load_lds(16B) with pre-swizzled source
// (linear LDS dest + XOR-swizzled ds_read). BK=64. Wave = 64x64 output.
template <int BM, int BN, bool RELU, bool OUTBF>
__global__ __launch_bounds__((BM / 64) * (BN / 64) * 64) void bf16_gemm_kernel(
    const short* __restrict__ A, const short* __restrict__ Bt,
    const float* __restrict__ bias, void* __restrict__ Cv, int M, int N,
    int K) {
  constexpr int WM = BM / 64, WN = BN / 64, NW = WM * WN;
  constexpr int AISS = BM / (NW * 8), BISS = BN / (NW * 8);
  __shared__ short As[BM * 64];
  __shared__ short Bs[BN * 64];
  const int tid = threadIdx.x, lane = tid & 63, w = tid >> 6;
  const int wr = w / WN, wc = w % WN;
  const int lhi = lane >> 4, llo = lane & 15;

  // bijective XCD swizzle (nwg % 8 == 0 for all our shapes)
  const int gx = gridDim.x;
  const int nwg = gx * gridDim.y;
  int lin = blockIdx.y * gx + blockIdx.x;
  if ((nwg & 7) == 0) lin = (lin & 7) * (nwg >> 3) + (lin >> 3);
  const int bm = (lin / gx) * BM, bn = (lin % gx) * BN;

  const int arow = lane >> 3;                       // row within 8-row issue
  const int achunk = ((lane & 7) ^ (lane >> 3)) * 8;  // pre-swizzled k-chunk

  f32x4 acc[4][4];
#pragma unroll
  for (int i = 0; i < 4; ++i)
#pragma unroll
    for (int j = 0; j < 4; ++j) acc[i][j] = (f32x4)0.f;

  char* AsB = (char*)As;
  char* BsB = (char*)Bs;

  for (int k0 = 0; k0 < K; k0 += 64) {
#pragma unroll
    for (int g = 0; g < AISS; ++g) {
      const int r0 = (w * AISS + g) * 8;
      const short* gp = A + (size_t)(bm + r0 + arow) * K + k0 + achunk;
      __builtin_amdgcn_global_load_lds(
          (const __attribute__((address_space(1))) void*)gp,
          (__attribute__((address_space(3))) void*)&As[r0 * 64], 16, 0, 0);
    }
#pragma unroll
    for (int g = 0; g < BISS; ++g) {
      const int r0 = (w * BISS + g) * 8;
      const short* gp = Bt + (size_t)(bn + r0 + arow) * K + k0 + achunk;
      __builtin_amdgcn_global_load_lds(
          (const __attribute__((address_space(1))) void*)gp,
          (__attribute__((address_space(3))) void*)&Bs[r0 * 64], 16, 0, 0);
    }
    __syncthreads();
#pragma unroll
    for (int ks = 0; ks < 2; ++ks) {
      short8 af[4], bf[4];
#pragma unroll
      for (int i = 0; i < 4; ++i)
        af[i] = *(const short8*)(AsB +
                                 swzb(wr * 64 + i * 16 + llo, ks * 64 + lhi * 16));
#pragma unroll
      for (int j = 0; j < 4; ++j)
        bf[j] = *(const short8*)(BsB +
                                 swzb(wc * 64 + j * 16 + llo, ks * 64 + lhi * 16));
#pragma unroll
      for (int i = 0; i < 4; ++i)
#pragma unroll
        for (int j = 0; j < 4; ++j)
          acc[i][j] = __builtin_amdgcn_mfma_f32_16x16x32_bf16(af[i], bf[j],
                                                              acc[i][j], 0, 0, 0);
    }
    __syncthreads();
  }
  // epilogue: C/D layout col=lane&15, row=(lane>>4)*4+r
#pragma unroll
  for (int j = 0; j < 4; ++j) {
    const int col = bn + wc * 64 + j * 16 + llo;
    const float bv = bias ? bias[col] : 0.f;
#pragma unroll
    for (int i = 0; i < 4; ++i) {
      const int row0 = bm + wr * 64 + i * 16 + lhi * 4;
#pragma unroll
      for (int r = 0; r < 4; ++r) {
        float v = acc[i][j][r] + bv;
        if (RELU) v = fmaxf(v, 0.f);
        if (OUTBF)
          ((short*)Cv)[(size_t)(row0 + r) * N + col] = f2bf(v);
        else
          ((float*)Cv)[(size_t)(row0 + r) * N + col] = v;
      }
    }
  }
}

// ============ fallback f32 SIMT GEMM (only if ws too small for outWt) =======
template <int BM, int BN, int BK, int TM, int TN>
__global__ __launch_bounds__((BM / TM) * (BN / TN)) void gemm_f32_kernel(
    const float* __restrict__ A, const float* __restrict__ B,
    const float* __restrict__ bias, float* __restrict__ C, int M, int N,
    int K) {
  constexpr int THREADS = (BM / TM) * (BN / TN);
  __shared__ float As[BK][BM + 1];
  __shared__ float Bs[BK][BN + 1];
  const int tid = threadIdx.x;
  const int bm = blockIdx.y * BM, bn = blockIdx.x * BN;
  const int tcol = tid % (BN / TN), trow = tid / (BN / TN);
  float acc[TM][TN];
#pragma unroll
  for (int i = 0; i < TM; ++i)
#pragma unroll
    for (int j = 0; j < TN; ++j) acc[i][j] = 0.f;
  for (int k0 = 0; k0 < K; k0 += BK) {
    for (int i = tid; i < BM * BK; i += THREADS) {
      int m = i / BK, kk = i % BK;
      As[kk][m] = A[(size_t)(bm + m) * K + (k0 + kk)];
    }
    for (int i = tid; i < BK * BN; i += THREADS) {
      int kk = i / BN, n = i % BN;
      Bs[kk][n] = B[(size_t)(k0 + kk) * N + (bn + n)];
    }
    __syncthreads();
#pragma unroll
    for (int kk = 0; kk < BK; ++kk) {
      float a[TM], b[TN];
#pragma unroll
      for (int i = 0; i < TM; ++i) a[i] = As[kk][trow * TM + i];
#pragma unroll
      for (int j = 0; j < TN; ++j) b[j] = Bs[kk][tcol * TN + j];
#pragma unroll
      for (int i = 0; i < TM; ++i)
#pragma unroll
        for (int j = 0; j < TN; ++j) acc[i][j] += a[i] * b[j];
    }
    __syncthreads();
  }
#pragma unroll
  for (int i = 0; i < TM; ++i) {
    int m = bm + trow * TM + i;
#pragma unroll
    for (int j = 0; j < TN; ++j) {
      int n = bn + tcol * TN + j;
      C[(size_t)m * N + n] = acc[i][j] + (bias ? bias[n] : 0.f);
    }
  }
}

// ============ token + positional embedding (f32 + bf16 copies) ==============
__global__ void embed_kernel(const int* __restrict__ captions,
                             const float* __restrict__ emb,
                             const float* __restrict__ pos,
                             float* __restrict__ x, short* __restrict__ xb) {
  int idx = blockIdx.x * blockDim.x + threadIdx.x;
  int d = idx % D_;
  int nt = idx / D_;
  int t = nt % T_;
  int tok = captions[nt];
  float v = emb[(size_t)tok * D_ + d] + pos[(size_t)t * D_ + d];
  x[idx] = v;
  xb[idx] = f2bf(v);
}

// ============ tiny-M matmul: one wave per output element, lanes split K =====
__global__ __launch_bounds__(256) void wave_mm_kernel(
    const float* __restrict__ A, const float* __restrict__ W,
    const float* __restrict__ bias, float* __restrict__ out, int M, int K,
    int N) {
  const int widx = blockIdx.x * 4 + (threadIdx.x >> 6);
  const int lane = threadIdx.x & 63;
  if (widx >= M * N) return;
  const int m = widx / N, n = widx % N;
  const float* a = A + (size_t)m * K;
  const float* w = W + n;
  float s = 0.f;
  for (int k = lane; k < K; k += 64) s += a[k] * w[(size_t)k * N];
#pragma unroll
  for (int off = 32; off; off >>= 1) s += __shfl_xor(s, off);
  if (lane == 0) out[widx] = s + (bias ? bias[n] : 0.f);
}

// ============ MFMA flash attention (bf16 in / bf16 out) =====================
// qkv: [N*T][1536] bf16 rows (q|k|v). Block = 4 waves, one (n,h,64-row Qtile).
__global__ __launch_bounds__(256) void flash_attn_kernel(
    const short* __restrict__ qkv, short* __restrict__ y) {
  __shared__ short Ks[64 * 64];     // [s][d] bf16, swizzled
  __shared__ short Vt[64 * 64];     // [d][s] bf16, swizzled
  __shared__ short Ps[4][16 * 64];  // per-wave [t][s] bf16, swizzled
  const int t0 = blockIdx.x * 64;
  const int h = blockIdx.y, n = blockIdx.z;
  const int tid = threadIdx.x, lane = tid & 63, w = tid >> 6;
  const int lhi = lane >> 4, llo = lane & 15;
  char* KsB = (char*)Ks;
  char* VtB = (char*)Vt;
  char* PsB = (char*)Ps[w];

  const short* qrow = qkv + (size_t)(n * T_ + t0 + w * 16 + llo) * 1536 + h * 64;
  short8 qf[2];
#pragma unroll
  for (int kc = 0; kc < 2; ++kc) qf[kc] = *(const short8*)(qrow + kc * 32 + lhi * 8);

  float m = -1e30f, l = 0.f;
  f32x4 acc[4];
#pragma unroll
  for (int dc = 0; dc < 4; ++dc) acc[dc] = (f32x4)0.f;

  const int arow = lane >> 3;
  const int achunk = ((lane & 7) ^ (lane >> 3)) * 8;  // pre-swizzled chunk
  const int vr = tid >> 2, vd0 = (tid & 3) * 16;      // V-scatter assignment
  const int tg = t0 + w * 16 + llo;

  for (int s0 = 0; s0 <= t0; s0 += 64) {
    __syncthreads();  // prev chunk's LDS reads done before overwrite
    // K tile via global_load_lds, pre-swizzled source (2 issues/wave)
#pragma unroll
    for (int g = 0; g < 2; ++g) {
      const int r0 = w * 16 + g * 8;
      const short* gp =
          qkv + (size_t)(n * T_ + s0 + r0 + arow) * 1536 + 512 + h * 64 + achunk;
      __builtin_amdgcn_global_load_lds(
          (const __attribute__((address_space(1))) void*)gp,
          (__attribute__((address_space(3))) void*)&Ks[r0 * 64], 16, 0, 0);
    }
    // V tile: reg-staged transpose scatter into Vt[d][s]
    {
      const short* vg =
          qkv + (size_t)(n * T_ + s0 + vr) * 1536 + 1024 + h * 64 + vd0;
      short8 v0 = *(const short8*)(vg);
      short8 v1 = *(const short8*)(vg + 8);
#pragma unroll
      for (int j = 0; j < 8; ++j) {
        *(short*)(VtB + swzb(vd0 + j, vr * 2)) = v0[j];
        *(short*)(VtB + swzb(vd0 + 8 + j, vr * 2)) = v1[j];
      }
    }
    __syncthreads();

    // S^T tiles: mfma(K, Q) -> per lane: t=llo, s=tile*16+lhi*4+r
    f32x4 st[4];
#pragma unroll
    for (int tile = 0; tile < 4; ++tile) {
      st[tile] = (f32x4)0.f;
#pragma unroll
      for (int kc = 0; kc < 2; ++kc) {
        short8 kf =
            *(const short8*)(KsB + swzb(tile * 16 + llo, kc * 64 + lhi * 16));
        st[tile] =
            __builtin_amdgcn_mfma_f32_16x16x32_bf16(kf, qf[kc], st[tile], 0, 0, 0);
      }
#pragma unroll
      for (int r = 0; r < 4; ++r) st[tile][r] *= 0.125f;  // 1/sqrt(64)
    }
    if (s0 == t0) {  // diagonal chunk: causal mask
#pragma unroll
      for (int tile = 0; tile < 4; ++tile)
#pragma unroll
        for (int r = 0; r < 4; ++r)
          if (s0 + tile * 16 + lhi * 4 + r > tg) st[tile][r] = -1e30f;
    }
    float cmax = -1e30f;
#pragma unroll
    for (int tile = 0; tile < 4; ++tile)
#pragma unroll
      for (int r = 0; r < 4; ++r) cmax = fmaxf(cmax, st[tile][r]);
    cmax = fmaxf(cmax, __shfl_xor(cmax, 16));
    cmax = fmaxf(cmax, __shfl_xor(cmax, 32));
    float mn = fmaxf(m, cmax);
    float corr = __expf(m - mn);
    float lsum = 0.f;
#pragma unroll
    for (int tile = 0; tile < 4; ++tile)
#pragma unroll
      for (int r = 0; r < 4; ++r) {
        float p = __expf(st[tile][r] - mn);
        st[tile][r] = p;
        lsum += p;
      }
    lsum += __shfl_xor(lsum, 16);
    lsum += __shfl_xor(lsum, 32);
    l = l * corr + lsum;
    m = mn;
#pragma unroll
    for (int tile = 0; tile < 4; ++tile) {
      int base = swzb(llo, tile * 32 + lhi * 8);
      *(uint32_t*)(PsB + base) = pack_bf2(st[tile][0], st[tile][1]);
      *(uint32_t*)(PsB + base + 4) = pack_bf2(st[tile][2], st[tile][3]);
    }
    float c0 = __shfl(corr, lhi * 4 + 0), c1 = __shfl(corr, lhi * 4 + 1);
    float c2 = __shfl(corr, lhi * 4 + 2), c3 = __shfl(corr, lhi * 4 + 3);
#pragma unroll
    for (int dc = 0; dc < 4; ++dc) {
      acc[dc][0] *= c0;
      acc[dc][1] *= c1;
      acc[dc][2] *= c2;
      acc[dc][3] *= c3;
    }
    short8 pf0 = *(const short8*)(PsB + swzb(llo, lhi * 16));
    short8 pf1 = *(const short8*)(PsB + swzb(llo, 64 + lhi * 16));
#pragma unroll
    for (int dc = 0; dc < 4; ++dc) {
      short8 vf0 = *(const short8*)(VtB + swzb(dc * 16 + llo, lhi * 16));
      short8 vf1 = *(const short8*)(VtB + swzb(dc * 16 + llo, 64 + lhi * 16));
      acc[dc] = __builtin_amdgcn_mfma_f32_16x16x32_bf16(pf0, vf0, acc[dc], 0, 0, 0);
      acc[dc] = __builtin_amdgcn_mfma_f32_16x16x32_bf16(pf1, vf1, acc[dc], 0, 0, 0);
    }
  }

  float linv = 1.f / l;
  float l0 = __shfl(linv, lhi * 4 + 0), l1 = __shfl(linv, lhi * 4 + 1);
  float l2 = __shfl(linv, lhi * 4 + 2), l3 = __shfl(linv, lhi * 4 + 3);
  short* yb = y + (size_t)(n * T_ + t0 + w * 16) * D_ + h * 64;
#pragma unroll
  for (int dc = 0; dc < 4; ++dc) {
    yb[(size_t)(lhi * 4 + 0) * D_ + dc * 16 + llo] = f2bf(acc[dc][0] * l0);
    yb[(size_t)(lhi * 4 + 1) * D_ + dc * 16 + llo] = f2bf(acc[dc][1] * l1);
    yb[(size_t)(lhi * 4 + 2) * D_ + dc * 16 + llo] = f2bf(acc[dc][2] * l2);
    yb[(size_t)(lhi * 4 + 3) * D_ + dc * 16 + llo] = f2bf(acc[dc][3] * l3);
  }
}

// ============ fused residual add + LayerNorm (writes f32 x + bf16 xb) =======
__global__ __launch_bounds__(256) void ln_res_kernel(
    float* __restrict__ x, short* __restrict__ xb, const float* __restrict__ res,
    const float* __restrict__ g, const float* __restrict__ b,
    int resBroadcast) {
  const int row = blockIdx.x;
  const int tid = threadIdx.x;
  float* xr = x + (size_t)row * D_;
  short* xbr = xb + (size_t)row * D_;
  const float* rr =
      res + (resBroadcast ? (size_t)(row / T_) * D_ : (size_t)row * D_);
  float v0 = xr[tid] + rr[tid];
  float v1 = xr[tid + 256] + rr[tid + 256];
  float s = v0 + v1, sq = v0 * v0 + v1 * v1;
#pragma unroll
  for (int off = 32; off; off >>= 1) {
    s += __shfl_xor(s, off);
    sq += __shfl_xor(sq, off);
  }
  __shared__ float ss[4], ssq[4];
  int wid = tid >> 6;
  if ((tid & 63) == 0) {
    ss[wid] = s;
    ssq[wid] = sq;
  }
  __syncthreads();
  s = ss[0] + ss[1] + ss[2] + ss[3];
  sq = ssq[0] + ssq[1] + ssq[2] + ssq[3];
  float mu = s * (1.f / D_);
  float var = sq * (1.f / D_) - mu * mu;
  float r = rsqrtf(var + 1e-5f);
  float o0 = (v0 - mu) * r * g[tid] + b[tid];
  float o1 = (v1 - mu) * r * g[tid + 256] + b[tid + 256];
  xr[tid] = o0;
  xr[tid + 256] = o1;
  xbr[tid] = f2bf(o0);
  xbr[tid + 256] = f2bf(o1);
}

// ============ host orchestration ============================================
extern "C" void kernel_launch(void* const* d_in, const int* in_sizes, int n_in,
                              void* d_out, int out_size, void* d_ws,
                              size_t ws_size, hipStream_t stream) {
  const float* features = (const float*)d_in[0];
  const int* captions = (const int*)d_in[1];
  const float* emb_table = (const float*)d_in[2];
  const float* pos_table = (const float*)d_in[3];
  const float* feat_W = (const float*)d_in[4];
  const float* feat_b = (const float*)d_in[5];
  const float* sa_qkv_W = (const float*)d_in[6];
  const float* sa_qkv_b = (const float*)d_in[7];
  const float* sa_o_W = (const float*)d_in[8];
  const float* sa_o_b = (const float*)d_in[9];
  const float* sa_ln = (const float*)d_in[10];
  const float* ca_qkv_W = (const float*)d_in[11];
  const float* ca_qkv_b = (const float*)d_in[12];
  const float* ca_o_W = (const float*)d_in[13];
  const float* ca_o_b = (const float*)d_in[14];
  const float* ca_ln = (const float*)d_in[15];
  const float* ff_W1 = (const float*)d_in[16];
  const float* ff_b1 = (const float*)d_in[17];
  const float* ff_W2 = (const float*)d_in[18];
  const float* ff_b2 = (const float*)d_in[19];
  const float* ff_ln = (const float*)d_in[20];
  const float* out_W = (const float*)d_in[21];
  const float* out_b = (const float*)d_in[22];

  const int ROWS = N_ * T_;  // 4096
  float* out = (float*)d_out;

  // ---- ws scratch ---------------------------------------------------------
  float* x = (float*)d_ws;                    // ROWS*D f32
  short* xb = (short*)(x + (size_t)ROWS * D_);  // ROWS*D bf16
  float* cond = (float*)(xb + (size_t)ROWS * D_);
  float* vc = cond + N_ * D_;
  float* oc = vc + N_ * D_;
  short* outWt = (short*)(oc + N_ * D_);
  size_t ws_need = (size_t)ROWS * D_ * 6 + 3 * N_ * D_ * 4 + (size_t)V_ * D_ * 2;
  const bool big_ws = ws_size >= ws_need;

  // ---- d_out scratch (consumed before the final GEMM overwrites) ----------
  short* qkvb = (short*)out;                     // ROWS*1536 bf16
  short* yb = qkvb + (size_t)ROWS * 3 * D_;      // ROWS*D bf16
  short* ffhb = yb + (size_t)ROWS * D_;          // ROWS*F bf16
  float* tmp = (float*)(ffhb + (size_t)ROWS * F_);  // ROWS*D f32
  short* wq = (short*)(tmp + (size_t)ROWS * D_);    // L*3*D rows of [D]
  short* wo = wq + (size_t)L_ * 3 * D_ * D_;        // L*D rows of [D]
  short* w1 = wo + (size_t)L_ * D_ * D_;            // L*F rows of [D]
  short* w2 = w1 + (size_t)L_ * F_ * D_;            // L*D rows of [F]

  // ---- weight transposes + bf16 conversion --------------------------------
  hipLaunchKernelGGL(transpose_bf16_kernel, dim3(D_ / 64, D_ / 64, L_ * 3),
                     dim3(256), 0, stream, sa_qkv_W, wq, D_, D_);
  hipLaunchKernelGGL(transpose_bf16_kernel, dim3(F_ / 64, D_ / 64, L_),
                     dim3(256), 0, stream, ff_W1, w1, D_, F_);
  hipLaunchKernelGGL(transpose_bf16_kernel, dim3(D_ / 64, D_ / 64, L_),
                     dim3(256), 0, stream, sa_o_W, wo, D_, D_);
  hipLaunchKernelGGL(transpose_bf16_kernel, dim3(D_ / 64, F_ / 64, L_),
                     dim3(256), 0, stream, ff_W2, w2, F_, D_);
  if (big_ws)
    hipLaunchKernelGGL(transpose_bf16_kernel, dim3(V_ / 64, D_ / 64, 1),
                       dim3(256), 0, stream, out_W, outWt, D_, V_);

  // big GEMM: 256x128 tile, 512 thr; small GEMM: 128x128 tile, 256 thr
  auto mgBig = [&](const short* A, const short* Bt, const float* bias, void* C,
                   int M, int Nn, int K, bool relu, bool outbf) {
    dim3 grid(Nn / 128, M / 256);
    if (relu)
      hipLaunchKernelGGL((bf16_gemm_kernel<256, 128, true, true>), grid,
                         dim3(512), 0, stream, A, Bt, bias, C, M, Nn, K);
    else if (outbf)
      hipLaunchKernelGGL((bf16_gemm_kernel<256, 128, false, true>), grid,
                         dim3(512), 0, stream, A, Bt, bias, C, M, Nn, K);
    else
      hipLaunchKernelGGL((bf16_gemm_kernel<256, 128, false, false>), grid,
                         dim3(512), 0, stream, A, Bt, bias, C, M, Nn, K);
  };
  auto mgSmall = [&](const short* A, const short* Bt, const float* bias,
                     float* C, int M, int Nn, int K) {
    dim3 grid(Nn / 128, M / 128);
    hipLaunchKernelGGL((bf16_gemm_kernel<128, 128, false, false>), grid,
                       dim3(256), 0, stream, A, Bt, bias, C, M, Nn, K);
  };
  auto wmm = [&](const float* A, const float* W, const float* bias, float* C,
                 int M, int K, int Nn) {
    hipLaunchKernelGGL(wave_mm_kernel, dim3((M * Nn + 3) / 4), dim3(256), 0,
                       stream, A, W, bias, C, M, K, Nn);
  };

  // ---- cond + embedding ---------------------------------------------------
  wmm(features, feat_W, feat_b, cond, N_, DIN_, D_);
  hipLaunchKernelGGL(embed_kernel, dim3(ROWS * D_ / 256), dim3(256), 0, stream,
                     captions, emb_table, pos_table, x, xb);

  for (int l = 0; l < L_; ++l) {
    // fused QKV projection: [4096,512] @ [512,1536] -> bf16
    mgBig(xb, wq + (size_t)l * 3 * D_ * D_, sa_qkv_b + (size_t)l * 3 * D_, qkvb,
          ROWS, 3 * D_, D_, false, true);
    hipLaunchKernelGGL(flash_attn_kernel, dim3(T_ / 64, H_, N_), dim3(256), 0,
                       stream, qkvb, yb);
    mgSmall(yb, wo + (size_t)l * D_ * D_, sa_o_b + (size_t)l * D_, tmp, ROWS,
            D_, D_);
    hipLaunchKernelGGL(ln_res_kernel, dim3(ROWS), dim3(256), 0, stream, x, xb,
                       tmp, sa_ln + (size_t)l * 2 * D_,
                       sa_ln + (size_t)l * 2 * D_ + D_, 0);

    // cross-attention (KV len 1 -> softmax == 1): v_c @ Wo broadcast
    wmm(cond, ca_qkv_W + (size_t)(l * 3 + 2) * D_ * D_,
        ca_qkv_b + (size_t)(l * 3 + 2) * D_, vc, N_, D_, D_);
    wmm(vc, ca_o_W + (size_t)l * D_ * D_, ca_o_b + (size_t)l * D_, oc, N_, D_,
        D_);
    hipLaunchKernelGGL(ln_res_kernel, dim3(ROWS), dim3(256), 0, stream, x, xb,
                       oc, ca_ln + (size_t)l * 2 * D_,
                       ca_ln + (size_t)l * 2 * D_ + D_, 1);

    // FFN
    mgBig(xb, w1 + (size_t)l * F_ * D_, ff_b1 + (size_t)l * F_, ffhb, ROWS, F_,
          D_, true, true);
    mgSmall(ffhb, w2 + (size_t)l * D_ * F_, ff_b2 + (size_t)l * D_, tmp, ROWS,
            D_, F_);
    hipLaunchKernelGGL(ln_res_kernel, dim3(ROWS), dim3(256), 0, stream, x, xb,
                       tmp, ff_ln + (size_t)l * 2 * D_,
                       ff_ln + (size_t)l * 2 * D_ + D_, 0);
  }

  // ---- final vocab projection --------------------------------------------
  if (big_ws) {
    mgBig(xb, outWt, out_b, out, ROWS, V_, D_, false, false);
  } else {
    dim3 grid(V_ / 64, ROWS / 128);
    hipLaunchKernelGGL((gemm_f32_kernel<128, 64, 16, 8, 4>), grid, dim3(256), 0,
                       stream, x, out_W, out_b, out, ROWS, V_, D_);
  }
}